// Round 1
// baseline (2322.060 us; speedup 1.0000x reference)
//
#include <hip/hip_runtime.h>
#include <hip/hip_bf16.h>

#define NN 200000
#define NE 600000
#define CH 256

typedef short bf16x8 __attribute__((ext_vector_type(8)));
typedef float f32x4 __attribute__((ext_vector_type(4)));

__device__ __forceinline__ unsigned short f2bf(float f) {
    unsigned int u = __builtin_bit_cast(unsigned int, f);
    u = (u + 0x7FFFu + ((u >> 16) & 1u)) >> 16;
    return (unsigned short)u;
}

// K0: Wt[j][k] = bf16(W[k][j])  (transpose so B-fragments are k-contiguous)
__global__ void k_wt(const float* __restrict__ W, unsigned short* __restrict__ Wt) {
    int j = blockIdx.x, k = threadIdx.x;
    Wt[j * CH + k] = f2bf(W[k * CH + j]);
}

// K1: agg = x  (agg lives in d_out)
__global__ void k_copy(const float4* __restrict__ s, float4* __restrict__ d, int n4) {
    int i = blockIdx.x * blockDim.x + threadIdx.x;
    int st = gridDim.x * blockDim.x;
    for (; i < n4; i += st) d[i] = s[i];
}

// K2: agg[targets[e]] += x[sources[e]]  (64 lanes per edge, 4 floats per lane)
__global__ void k_scatter(const float* __restrict__ x, const int* __restrict__ se,
                          const int* __restrict__ te, float* __restrict__ agg) {
    int t = blockIdx.x * 256 + threadIdx.x;
    int e = t >> 6;
    if (e >= NE) return;
    int lane = t & 63;
    int s = se[e], d = te[e];
    float4 v = *reinterpret_cast<const float4*>(x + (size_t)s * CH + (size_t)lane * 4);
    float* p = agg + (size_t)d * CH + (size_t)lane * 4;
    atomicAdd(p + 0, v.x);
    atomicAdd(p + 1, v.y);
    atomicAdd(p + 2, v.z);
    atomicAdd(p + 3, v.w);
}

// K3: out = (norm * agg) @ W, in-place on d_out, bf16 MFMA 16x16x32.
// 4 waves/block, each wave computes 16 rows x 256 cols.
__global__ __launch_bounds__(256) void k_gemm(const float* __restrict__ norm,
                                              const unsigned short* __restrict__ Wt,
                                              float* __restrict__ out) {
    const int wid = threadIdx.x >> 6;
    const int lane = threadIdx.x & 63;
    const int m0 = blockIdx.x * 64 + wid * 16;
    const int arow_i = m0 + (lane & 15);
    const int kh = (lane >> 4) * 8;

    const float nrm = norm[arow_i];
    const float* arow = out + (size_t)arow_i * CH;

    f32x4 acc[16];
#pragma unroll
    for (int i = 0; i < 16; ++i) acc[i] = (f32x4){0.f, 0.f, 0.f, 0.f};

    const unsigned short* wbase = Wt + (size_t)(lane & 15) * CH + kh;

    for (int k0 = 0; k0 < CH; k0 += 32) {
        float4 a0 = *reinterpret_cast<const float4*>(arow + k0 + kh);
        float4 a1 = *reinterpret_cast<const float4*>(arow + k0 + kh + 4);
        bf16x8 af;
        af[0] = (short)f2bf(a0.x * nrm);
        af[1] = (short)f2bf(a0.y * nrm);
        af[2] = (short)f2bf(a0.z * nrm);
        af[3] = (short)f2bf(a0.w * nrm);
        af[4] = (short)f2bf(a1.x * nrm);
        af[5] = (short)f2bf(a1.y * nrm);
        af[6] = (short)f2bf(a1.z * nrm);
        af[7] = (short)f2bf(a1.w * nrm);
#pragma unroll
        for (int nt = 0; nt < 16; ++nt) {
            bf16x8 bfr = *reinterpret_cast<const bf16x8*>(wbase + (size_t)nt * 16 * CH + k0);
            acc[nt] = __builtin_amdgcn_mfma_f32_16x16x32_bf16(af, bfr, acc[nt], 0, 0, 0);
        }
    }

    const int crow = m0 + (lane >> 4) * 4;
    const int ccol = lane & 15;
#pragma unroll
    for (int nt = 0; nt < 16; ++nt) {
        float* po = out + (size_t)crow * CH + nt * 16 + ccol;
#pragma unroll
        for (int r = 0; r < 4; ++r) po[(size_t)r * CH] = acc[nt][r];
    }
}

extern "C" void kernel_launch(void* const* d_in, const int* in_sizes, int n_in,
                              void* d_out, int out_size, void* d_ws, size_t ws_size,
                              hipStream_t stream) {
    const float* x = (const float*)d_in[0];
    const int* se = (const int*)d_in[1];
    const int* te = (const int*)d_in[2];
    const float* norm = (const float*)d_in[3];
    const float* W = (const float*)d_in[4];
    float* out = (float*)d_out;
    unsigned short* Wt = (unsigned short*)d_ws;

    k_wt<<<CH, CH, 0, stream>>>(W, Wt);
    k_copy<<<2048, 256, 0, stream>>>((const float4*)x, (float4*)out, NN * CH / 4);
    k_scatter<<<(NE * 64) / 256, 256, 0, stream>>>(x, se, te, out);
    k_gemm<<<NN / 64, 256, 0, stream>>>(norm, Wt, out);
}

// Round 2
// 473.336 us; speedup vs baseline: 4.9057x; 4.9057x over previous
//
#include <hip/hip_runtime.h>
#include <hip/hip_bf16.h>

#define NN 200000
#define NE 600000
#define CH 256
#define NBLK_SCAN 196   // ceil(200000/1024)

typedef short bf16x8 __attribute__((ext_vector_type(8)));
typedef float f32x4 __attribute__((ext_vector_type(4)));

__device__ __forceinline__ unsigned short f2bf(float f) {
    unsigned int u = __builtin_bit_cast(unsigned int, f);
    u = (u + 0x7FFFu + ((u >> 16) & 1u)) >> 16;
    return (unsigned short)u;
}

// K0: Wt[j][k] = bf16(W[k][j])
__global__ void k_wt(const float* __restrict__ W, unsigned short* __restrict__ Wt) {
    int j = blockIdx.x, k = threadIdx.x;
    Wt[j * CH + k] = f2bf(W[k * CH + j]);
}

// zero the degree array
__global__ void k_zero(int* __restrict__ p, int n) {
    int i = blockIdx.x * 256 + threadIdx.x;
    if (i < n) p[i] = 0;
}

// count degrees per target
__global__ void k_count(const int* __restrict__ te, int* __restrict__ deg) {
    int e = blockIdx.x * 256 + threadIdx.x;
    if (e < NE) atomicAdd(&deg[te[e]], 1);
}

// exclusive scan, pass A: per-block (1024 items) scan + block sums
__global__ __launch_bounds__(256) void k_scanA(const int* __restrict__ deg,
                                               int* __restrict__ off,
                                               int* __restrict__ bsum) {
    __shared__ int ts[256];
    int tid = threadIdx.x;
    int base = blockIdx.x * 1024 + tid * 4;
    int v[4];
#pragma unroll
    for (int j = 0; j < 4; ++j) {
        int idx = base + j;
        v[j] = (idx < NN) ? deg[idx] : 0;
    }
    int tsum = v[0] + v[1] + v[2] + v[3];
    ts[tid] = tsum;
    __syncthreads();
    int x = tsum;
    for (int ofs = 1; ofs < 256; ofs <<= 1) {
        int y = (tid >= ofs) ? ts[tid - ofs] : 0;
        __syncthreads();
        x += y;
        ts[tid] = x;
        __syncthreads();
    }
    int run = x - tsum;  // exclusive prefix of this thread
#pragma unroll
    for (int j = 0; j < 4; ++j) {
        int idx = base + j;
        if (idx < NN) off[idx] = run;
        run += v[j];
    }
    if (tid == 255) bsum[blockIdx.x] = x;
}

// pass B: scan the block sums (NBLK_SCAN <= 256), in place -> exclusive
__global__ __launch_bounds__(256) void k_scanB(int* __restrict__ bsum) {
    __shared__ int ts[256];
    int tid = threadIdx.x;
    int v = (tid < NBLK_SCAN) ? bsum[tid] : 0;
    ts[tid] = v;
    __syncthreads();
    int x = v;
    for (int ofs = 1; ofs < 256; ofs <<= 1) {
        int y = (tid >= ofs) ? ts[tid - ofs] : 0;
        __syncthreads();
        x += y;
        ts[tid] = x;
        __syncthreads();
    }
    if (tid < NBLK_SCAN) bsum[tid] = x - v;
}

// pass C: add block offsets, init cursors
__global__ __launch_bounds__(256) void k_scanC(int* __restrict__ off,
                                               const int* __restrict__ bsum,
                                               int* __restrict__ cur) {
    int tid = threadIdx.x;
    int base = blockIdx.x * 1024 + tid * 4;
    int bo = bsum[blockIdx.x];
#pragma unroll
    for (int j = 0; j < 4; ++j) {
        int idx = base + j;
        if (idx < NN) {
            int o = off[idx] + bo;
            off[idx] = o;
            cur[idx] = o;
        }
    }
}

// fill CSR edge list: elist[pos] = source, bucketed by target
__global__ void k_fill(const int* __restrict__ se, const int* __restrict__ te,
                       int* __restrict__ cur, int* __restrict__ elist) {
    int e = blockIdx.x * 256 + threadIdx.x;
    if (e < NE) {
        int t = te[e];
        int pos = atomicAdd(&cur[t], 1);
        elist[pos] = se[e];
    }
}

// gather: one wave per row; agg[row] = x[row] + sum_e x[elist[e]]
__global__ __launch_bounds__(256) void k_gather(const float* __restrict__ x,
                                                const int* __restrict__ off,
                                                const int* __restrict__ deg,
                                                const int* __restrict__ elist,
                                                float* __restrict__ out) {
    int wid = threadIdx.x >> 6;
    int lane = threadIdx.x & 63;
    int row = blockIdx.x * 4 + wid;
    if (row >= NN) return;
    int start = off[row];
    int d = deg[row];
    size_t loff = (size_t)lane * 4;
    float4 acc = *reinterpret_cast<const float4*>(x + (size_t)row * CH + loff);
    int e = 0;
    for (; e + 2 <= d; e += 2) {
        int s0 = elist[start + e];
        int s1 = elist[start + e + 1];
        float4 v0 = *reinterpret_cast<const float4*>(x + (size_t)s0 * CH + loff);
        float4 v1 = *reinterpret_cast<const float4*>(x + (size_t)s1 * CH + loff);
        acc.x += v0.x + v1.x; acc.y += v0.y + v1.y;
        acc.z += v0.z + v1.z; acc.w += v0.w + v1.w;
    }
    if (e < d) {
        int s0 = elist[start + e];
        float4 v0 = *reinterpret_cast<const float4*>(x + (size_t)s0 * CH + loff);
        acc.x += v0.x; acc.y += v0.y; acc.z += v0.z; acc.w += v0.w;
    }
    *reinterpret_cast<float4*>(out + (size_t)row * CH + loff) = acc;
}

// GEMM: out = (norm * agg) @ W, in-place on d_out, bf16 MFMA 16x16x32.
__global__ __launch_bounds__(256) void k_gemm(const float* __restrict__ norm,
                                              const unsigned short* __restrict__ Wt,
                                              float* __restrict__ out) {
    const int wid = threadIdx.x >> 6;
    const int lane = threadIdx.x & 63;
    const int m0 = blockIdx.x * 64 + wid * 16;
    const int arow_i = m0 + (lane & 15);
    const int kh = (lane >> 4) * 8;

    const float nrm = norm[arow_i];
    const float* arow = out + (size_t)arow_i * CH;

    f32x4 acc[16];
#pragma unroll
    for (int i = 0; i < 16; ++i) acc[i] = (f32x4){0.f, 0.f, 0.f, 0.f};

    const unsigned short* wbase = Wt + (size_t)(lane & 15) * CH + kh;

    for (int k0 = 0; k0 < CH; k0 += 32) {
        float4 a0 = *reinterpret_cast<const float4*>(arow + k0 + kh);
        float4 a1 = *reinterpret_cast<const float4*>(arow + k0 + kh + 4);
        bf16x8 af;
        af[0] = (short)f2bf(a0.x * nrm);
        af[1] = (short)f2bf(a0.y * nrm);
        af[2] = (short)f2bf(a0.z * nrm);
        af[3] = (short)f2bf(a0.w * nrm);
        af[4] = (short)f2bf(a1.x * nrm);
        af[5] = (short)f2bf(a1.y * nrm);
        af[6] = (short)f2bf(a1.z * nrm);
        af[7] = (short)f2bf(a1.w * nrm);
#pragma unroll
        for (int nt = 0; nt < 16; ++nt) {
            bf16x8 bfr = *reinterpret_cast<const bf16x8*>(wbase + (size_t)nt * 16 * CH + k0);
            acc[nt] = __builtin_amdgcn_mfma_f32_16x16x32_bf16(af, bfr, acc[nt], 0, 0, 0);
        }
    }

    const int crow = m0 + (lane >> 4) * 4;
    const int ccol = lane & 15;
#pragma unroll
    for (int nt = 0; nt < 16; ++nt) {
        float* po = out + (size_t)crow * CH + nt * 16 + ccol;
#pragma unroll
        for (int r = 0; r < 4; ++r) po[(size_t)r * CH] = acc[nt][r];
    }
}

extern "C" void kernel_launch(void* const* d_in, const int* in_sizes, int n_in,
                              void* d_out, int out_size, void* d_ws, size_t ws_size,
                              hipStream_t stream) {
    const float* x = (const float*)d_in[0];
    const int* se = (const int*)d_in[1];
    const int* te = (const int*)d_in[2];
    const float* norm = (const float*)d_in[3];
    const float* W = (const float*)d_in[4];
    float* out = (float*)d_out;

    char* ws = (char*)d_ws;
    unsigned short* Wt = (unsigned short*)ws;            // 128 KB
    int* deg   = (int*)(ws + 131072);                    // 800 KB
    int* off   = (int*)(ws + 931072);                    // 800 KB
    int* cur   = (int*)(ws + 1731072);                   // 800 KB
    int* elist = (int*)(ws + 2531072);                   // 2.4 MB
    int* bsum  = (int*)(ws + 4931072);                   // 1 KB

    k_wt<<<CH, CH, 0, stream>>>(W, Wt);
    k_zero<<<(NN + 255) / 256, 256, 0, stream>>>(deg, NN);
    k_count<<<(NE + 255) / 256, 256, 0, stream>>>(te, deg);
    k_scanA<<<NBLK_SCAN, 256, 0, stream>>>(deg, off, bsum);
    k_scanB<<<1, 256, 0, stream>>>(bsum);
    k_scanC<<<NBLK_SCAN, 256, 0, stream>>>(off, bsum, cur);
    k_fill<<<(NE + 255) / 256, 256, 0, stream>>>(se, te, cur, elist);
    k_gather<<<(NN + 3) / 4, 256, 0, stream>>>(x, off, deg, elist, out);
    k_gemm<<<NN / 64, 256, 0, stream>>>(norm, Wt, out);
}

// Round 3
// 407.762 us; speedup vs baseline: 5.6946x; 1.1608x over previous
//
#include <hip/hip_runtime.h>
#include <hip/hip_bf16.h>

#define NN 200000
#define NE 600000
#define CH 256
#define NBLK_SCAN 196   // ceil(200000/1024)

typedef short bf16x8 __attribute__((ext_vector_type(8)));
typedef float f32x4 __attribute__((ext_vector_type(4)));

__device__ __forceinline__ unsigned short f2bf(float f) {
    unsigned int u = __builtin_bit_cast(unsigned int, f);
    u = (u + 0x7FFFu + ((u >> 16) & 1u)) >> 16;
    return (unsigned short)u;
}

// K0: Wt[j][k] = bf16(W[k][j])
__global__ void k_wt(const float* __restrict__ W, unsigned short* __restrict__ Wt) {
    int j = blockIdx.x, k = threadIdx.x;
    Wt[j * CH + k] = f2bf(W[k * CH + j]);
}

__global__ void k_zero(int* __restrict__ p, int n) {
    int i = blockIdx.x * 256 + threadIdx.x;
    if (i < n) p[i] = 0;
}

__global__ void k_count(const int* __restrict__ te, int* __restrict__ deg) {
    int e = blockIdx.x * 256 + threadIdx.x;
    if (e < NE) atomicAdd(&deg[te[e]], 1);
}

__global__ __launch_bounds__(256) void k_scanA(const int* __restrict__ deg,
                                               int* __restrict__ off,
                                               int* __restrict__ bsum) {
    __shared__ int ts[256];
    int tid = threadIdx.x;
    int base = blockIdx.x * 1024 + tid * 4;
    int v[4];
#pragma unroll
    for (int j = 0; j < 4; ++j) {
        int idx = base + j;
        v[j] = (idx < NN) ? deg[idx] : 0;
    }
    int tsum = v[0] + v[1] + v[2] + v[3];
    ts[tid] = tsum;
    __syncthreads();
    int x = tsum;
    for (int ofs = 1; ofs < 256; ofs <<= 1) {
        int y = (tid >= ofs) ? ts[tid - ofs] : 0;
        __syncthreads();
        x += y;
        ts[tid] = x;
        __syncthreads();
    }
    int run = x - tsum;
#pragma unroll
    for (int j = 0; j < 4; ++j) {
        int idx = base + j;
        if (idx < NN) off[idx] = run;
        run += v[j];
    }
    if (tid == 255) bsum[blockIdx.x] = x;
}

__global__ __launch_bounds__(256) void k_scanB(int* __restrict__ bsum) {
    __shared__ int ts[256];
    int tid = threadIdx.x;
    int v = (tid < NBLK_SCAN) ? bsum[tid] : 0;
    ts[tid] = v;
    __syncthreads();
    int x = v;
    for (int ofs = 1; ofs < 256; ofs <<= 1) {
        int y = (tid >= ofs) ? ts[tid - ofs] : 0;
        __syncthreads();
        x += y;
        ts[tid] = x;
        __syncthreads();
    }
    if (tid < NBLK_SCAN) bsum[tid] = x - v;
}

__global__ __launch_bounds__(256) void k_scanC(int* __restrict__ off,
                                               const int* __restrict__ bsum,
                                               int* __restrict__ cur) {
    int tid = threadIdx.x;
    int base = blockIdx.x * 1024 + tid * 4;
    int bo = bsum[blockIdx.x];
#pragma unroll
    for (int j = 0; j < 4; ++j) {
        int idx = base + j;
        if (idx < NN) {
            int o = off[idx] + bo;
            off[idx] = o;
            cur[idx] = o;
        }
    }
}

__global__ void k_fill(const int* __restrict__ se, const int* __restrict__ te,
                       int* __restrict__ cur, int* __restrict__ elist) {
    int e = blockIdx.x * 256 + threadIdx.x;
    if (e < NE) {
        int t = te[e];
        int pos = atomicAdd(&cur[t], 1);
        elist[pos] = se[e];
    }
}

// gather: one wave per row; agg[row] = x[row] + sum_e x[elist[e]]
// Unrolled-8 index prefetch for MLP (all compile-time indexed).
__global__ __launch_bounds__(256) void k_gather(const float* __restrict__ x,
                                                const int* __restrict__ off,
                                                const int* __restrict__ deg,
                                                const int* __restrict__ elist,
                                                float* __restrict__ out) {
    int wid = threadIdx.x >> 6;
    int lane = threadIdx.x & 63;
    int row = blockIdx.x * 4 + wid;
    if (row >= NN) return;
    int start = off[row];
    int d = deg[row];
    size_t loff = (size_t)lane * 4;
    float4 acc = *reinterpret_cast<const float4*>(x + (size_t)row * CH + loff);
    int e = 0;
    while (e < d) {
        int i0 = (e + 0 < d) ? elist[start + e + 0] : -1;
        int i1 = (e + 1 < d) ? elist[start + e + 1] : -1;
        int i2 = (e + 2 < d) ? elist[start + e + 2] : -1;
        int i3 = (e + 3 < d) ? elist[start + e + 3] : -1;
        int i4 = (e + 4 < d) ? elist[start + e + 4] : -1;
        int i5 = (e + 5 < d) ? elist[start + e + 5] : -1;
        int i6 = (e + 6 < d) ? elist[start + e + 6] : -1;
        int i7 = (e + 7 < d) ? elist[start + e + 7] : -1;
#define GACC(ii) if (ii >= 0) { \
            float4 v = *reinterpret_cast<const float4*>(x + (size_t)ii * CH + loff); \
            acc.x += v.x; acc.y += v.y; acc.z += v.z; acc.w += v.w; }
        GACC(i0) GACC(i1) GACC(i2) GACC(i3) GACC(i4) GACC(i5) GACC(i6) GACC(i7)
#undef GACC
        e += 8;
    }
    *reinterpret_cast<float4*>(out + (size_t)row * CH + loff) = acc;
}

// GEMM: out = (norm * agg) @ W, in-place on d_out, bf16 MFMA 16x16x32.
// Each wave: 2 M-tiles (32 rows) x 256 cols. All 16 B-frags + both A-frag
// loads issued before MFMAs each k-step for deep MLP.
__global__ __launch_bounds__(256) void k_gemm(const float* __restrict__ norm,
                                              const unsigned short* __restrict__ Wt,
                                              float* __restrict__ out) {
    const int wid = threadIdx.x >> 6;
    const int lane = threadIdx.x & 63;
    const int t0 = blockIdx.x * 128 + wid * 16;   // always < NN (grid sized so)
    const int t1 = t0 + 64;
    const bool v1 = (t1 < NN);

    const int r0 = t0 + (lane & 15);
    const int r1 = v1 ? (t1 + (lane & 15)) : r0;  // safe address when inactive
    const int kh = (lane >> 4) * 8;

    const float n0 = norm[r0];
    const float n1 = norm[r1];
    const float* a0p = out + (size_t)r0 * CH + kh;
    const float* a1p = out + (size_t)r1 * CH + kh;

    f32x4 acc0[16], acc1[16];
#pragma unroll
    for (int i = 0; i < 16; ++i) {
        acc0[i] = (f32x4){0.f, 0.f, 0.f, 0.f};
        acc1[i] = (f32x4){0.f, 0.f, 0.f, 0.f};
    }

    const unsigned short* wb = Wt + (size_t)(lane & 15) * CH + kh;

    for (int k0 = 0; k0 < CH; k0 += 32) {
        // ---- issue all loads first ----
        bf16x8 b[16];
#pragma unroll
        for (int nt = 0; nt < 16; ++nt)
            b[nt] = *reinterpret_cast<const bf16x8*>(wb + (size_t)nt * 16 * CH + k0);
        float4 x00 = *reinterpret_cast<const float4*>(a0p + k0);
        float4 x01 = *reinterpret_cast<const float4*>(a0p + k0 + 4);
        float4 x10 = *reinterpret_cast<const float4*>(a1p + k0);
        float4 x11 = *reinterpret_cast<const float4*>(a1p + k0 + 4);
        // ---- convert ----
        bf16x8 af0, af1;
        af0[0] = (short)f2bf(x00.x * n0); af0[1] = (short)f2bf(x00.y * n0);
        af0[2] = (short)f2bf(x00.z * n0); af0[3] = (short)f2bf(x00.w * n0);
        af0[4] = (short)f2bf(x01.x * n0); af0[5] = (short)f2bf(x01.y * n0);
        af0[6] = (short)f2bf(x01.z * n0); af0[7] = (short)f2bf(x01.w * n0);
        af1[0] = (short)f2bf(x10.x * n1); af1[1] = (short)f2bf(x10.y * n1);
        af1[2] = (short)f2bf(x10.z * n1); af1[3] = (short)f2bf(x10.w * n1);
        af1[4] = (short)f2bf(x11.x * n1); af1[5] = (short)f2bf(x11.y * n1);
        af1[6] = (short)f2bf(x11.z * n1); af1[7] = (short)f2bf(x11.w * n1);
        // ---- compute ----
#pragma unroll
        for (int nt = 0; nt < 16; ++nt)
            acc0[nt] = __builtin_amdgcn_mfma_f32_16x16x32_bf16(af0, b[nt], acc0[nt], 0, 0, 0);
#pragma unroll
        for (int nt = 0; nt < 16; ++nt)
            acc1[nt] = __builtin_amdgcn_mfma_f32_16x16x32_bf16(af1, b[nt], acc1[nt], 0, 0, 0);
    }

    const int ccol = lane & 15;
    const int cr0 = t0 + (lane >> 4) * 4;
#pragma unroll
    for (int nt = 0; nt < 16; ++nt) {
        float* po = out + (size_t)cr0 * CH + nt * 16 + ccol;
#pragma unroll
        for (int r = 0; r < 4; ++r) po[(size_t)r * CH] = acc0[nt][r];
    }
    if (v1) {
        const int cr1 = t1 + (lane >> 4) * 4;
#pragma unroll
        for (int nt = 0; nt < 16; ++nt) {
            float* po = out + (size_t)cr1 * CH + nt * 16 + ccol;
#pragma unroll
            for (int r = 0; r < 4; ++r) po[(size_t)r * CH] = acc1[nt][r];
        }
    }
}

extern "C" void kernel_launch(void* const* d_in, const int* in_sizes, int n_in,
                              void* d_out, int out_size, void* d_ws, size_t ws_size,
                              hipStream_t stream) {
    const float* x = (const float*)d_in[0];
    const int* se = (const int*)d_in[1];
    const int* te = (const int*)d_in[2];
    const float* norm = (const float*)d_in[3];
    const float* W = (const float*)d_in[4];
    float* out = (float*)d_out;

    char* ws = (char*)d_ws;
    unsigned short* Wt = (unsigned short*)ws;            // 128 KB
    int* deg   = (int*)(ws + 131072);                    // 800 KB
    int* off   = (int*)(ws + 931072);                    // 800 KB
    int* cur   = (int*)(ws + 1731072);                   // 800 KB
    int* elist = (int*)(ws + 2531072);                   // 2.4 MB
    int* bsum  = (int*)(ws + 4931072);                   // 1 KB

    k_wt<<<CH, CH, 0, stream>>>(W, Wt);
    k_zero<<<(NN + 255) / 256, 256, 0, stream>>>(deg, NN);
    k_count<<<(NE + 255) / 256, 256, 0, stream>>>(te, deg);
    k_scanA<<<NBLK_SCAN, 256, 0, stream>>>(deg, off, bsum);
    k_scanB<<<1, 256, 0, stream>>>(bsum);
    k_scanC<<<NBLK_SCAN, 256, 0, stream>>>(off, bsum, cur);
    k_fill<<<(NE + 255) / 256, 256, 0, stream>>>(se, te, cur, elist);
    k_gather<<<(NN + 3) / 4, 256, 0, stream>>>(x, off, deg, elist, out);
    k_gemm<<<(NN + 127) / 128, 256, 0, stream>>>(norm, Wt, out);
}

// Round 4
// 405.125 us; speedup vs baseline: 5.7317x; 1.0065x over previous
//
#include <hip/hip_runtime.h>
#include <hip/hip_bf16.h>

#define NN 200000
#define NE 600000
#define CH 256
#define NBLK_SCAN 196   // ceil(200000/1024)
#define LSTR 264        // padded LDS row stride (bf16 elems)

typedef short bf16x8 __attribute__((ext_vector_type(8)));
typedef float f32x4 __attribute__((ext_vector_type(4)));

__device__ __forceinline__ unsigned short f2bf(float f) {
    unsigned int u = __builtin_bit_cast(unsigned int, f);
    u = (u + 0x7FFFu + ((u >> 16) & 1u)) >> 16;
    return (unsigned short)u;
}

// K0: Wt[j][k] = bf16(W[k][j])
__global__ void k_wt(const float* __restrict__ W, unsigned short* __restrict__ Wt) {
    int j = blockIdx.x, k = threadIdx.x;
    Wt[j * CH + k] = f2bf(W[k * CH + j]);
}

__global__ void k_zero(int* __restrict__ p, int n) {
    int i = blockIdx.x * 256 + threadIdx.x;
    if (i < n) p[i] = 0;
}

__global__ void k_count(const int* __restrict__ te, int* __restrict__ deg) {
    int e = blockIdx.x * 256 + threadIdx.x;
    if (e < NE) atomicAdd(&deg[te[e]], 1);
}

__global__ __launch_bounds__(256) void k_scanA(const int* __restrict__ deg,
                                               int* __restrict__ off,
                                               int* __restrict__ bsum) {
    __shared__ int ts[256];
    int tid = threadIdx.x;
    int base = blockIdx.x * 1024 + tid * 4;
    int v[4];
#pragma unroll
    for (int j = 0; j < 4; ++j) {
        int idx = base + j;
        v[j] = (idx < NN) ? deg[idx] : 0;
    }
    int tsum = v[0] + v[1] + v[2] + v[3];
    ts[tid] = tsum;
    __syncthreads();
    int x = tsum;
    for (int ofs = 1; ofs < 256; ofs <<= 1) {
        int y = (tid >= ofs) ? ts[tid - ofs] : 0;
        __syncthreads();
        x += y;
        ts[tid] = x;
        __syncthreads();
    }
    int run = x - tsum;
#pragma unroll
    for (int j = 0; j < 4; ++j) {
        int idx = base + j;
        if (idx < NN) off[idx] = run;
        run += v[j];
    }
    if (tid == 255) bsum[blockIdx.x] = x;
}

__global__ __launch_bounds__(256) void k_scanB(int* __restrict__ bsum) {
    __shared__ int ts[256];
    int tid = threadIdx.x;
    int v = (tid < NBLK_SCAN) ? bsum[tid] : 0;
    ts[tid] = v;
    __syncthreads();
    int x = v;
    for (int ofs = 1; ofs < 256; ofs <<= 1) {
        int y = (tid >= ofs) ? ts[tid - ofs] : 0;
        __syncthreads();
        x += y;
        ts[tid] = x;
        __syncthreads();
    }
    if (tid < NBLK_SCAN) bsum[tid] = x - v;
}

__global__ __launch_bounds__(256) void k_scanC(int* __restrict__ off,
                                               const int* __restrict__ bsum,
                                               int* __restrict__ cur) {
    int tid = threadIdx.x;
    int base = blockIdx.x * 1024 + tid * 4;
    int bo = bsum[blockIdx.x];
#pragma unroll
    for (int j = 0; j < 4; ++j) {
        int idx = base + j;
        if (idx < NN) {
            int o = off[idx] + bo;
            off[idx] = o;
            cur[idx] = o;
        }
    }
}

__global__ void k_fill(const int* __restrict__ se, const int* __restrict__ te,
                       int* __restrict__ cur, int* __restrict__ elist) {
    int e = blockIdx.x * 256 + threadIdx.x;
    if (e < NE) {
        int t = te[e];
        int pos = atomicAdd(&cur[t], 1);
        elist[pos] = se[e];
    }
}

// Fused gather + norm + GEMM. Each wave privately owns 16 output rows:
//  phase 1: agg rows in registers (base + CSR edges), *norm, bf16 -> LDS tile
//  phase 2: MFMA 16x16x32 with A from LDS, B (Wt) from L2.
// No __syncthreads needed: LDS rows are wave-private.
__global__ __launch_bounds__(256, 2) void k_fused(const float* __restrict__ x,
                                                  const int* __restrict__ off,
                                                  const int* __restrict__ deg,
                                                  const int* __restrict__ elist,
                                                  const float* __restrict__ norm,
                                                  const unsigned short* __restrict__ Wt,
                                                  float* __restrict__ out) {
    __shared__ unsigned short lds_a[64][LSTR];
    const int wid = threadIdx.x >> 6;
    const int lane = threadIdx.x & 63;
    const int rowbase = blockIdx.x * 64 + wid * 16;
    const int r16 = lane & 15;

    const int offv = off[rowbase + r16];
    const int degv = deg[rowbase + r16];
    const float normv = norm[rowbase + r16];
    const size_t loff = (size_t)lane * 4;
    unsigned short* lbase = &lds_a[wid * 16][0];

#pragma unroll
    for (int c = 0; c < 4; ++c) {
        const int s0 = __shfl(offv, 4 * c + 0), d0 = __shfl(degv, 4 * c + 0);
        const int s1 = __shfl(offv, 4 * c + 1), d1 = __shfl(degv, 4 * c + 1);
        const int s2 = __shfl(offv, 4 * c + 2), d2 = __shfl(degv, 4 * c + 2);
        const int s3 = __shfl(offv, 4 * c + 3), d3 = __shfl(degv, 4 * c + 3);

        float4 a0 = *reinterpret_cast<const float4*>(x + (size_t)(rowbase + 4 * c + 0) * CH + loff);
        float4 a1 = *reinterpret_cast<const float4*>(x + (size_t)(rowbase + 4 * c + 1) * CH + loff);
        float4 a2 = *reinterpret_cast<const float4*>(x + (size_t)(rowbase + 4 * c + 2) * CH + loff);
        float4 a3 = *reinterpret_cast<const float4*>(x + (size_t)(rowbase + 4 * c + 3) * CH + loff);

        int md = max(max(d0, d1), max(d2, d3));
        for (int e = 0; e < md; e += 2) {
            // wave-uniform guards (s*,d* are broadcast): scalar branches, no divergence
#define GROW(ss, dd, aa)                                                              \
            if (e < dd) {                                                             \
                int i0 = elist[ss + e];                                               \
                float4 v0 = *reinterpret_cast<const float4*>(x + (size_t)i0 * CH + loff); \
                aa.x += v0.x; aa.y += v0.y; aa.z += v0.z; aa.w += v0.w;               \
                if (e + 1 < dd) {                                                     \
                    int i1 = elist[ss + e + 1];                                       \
                    float4 v1 = *reinterpret_cast<const float4*>(x + (size_t)i1 * CH + loff); \
                    aa.x += v1.x; aa.y += v1.y; aa.z += v1.z; aa.w += v1.w;           \
                }                                                                     \
            }
            GROW(s0, d0, a0)
            GROW(s1, d1, a1)
            GROW(s2, d2, a2)
            GROW(s3, d3, a3)
#undef GROW
        }

        const float n0 = __shfl(normv, 4 * c + 0);
        const float n1 = __shfl(normv, 4 * c + 1);
        const float n2 = __shfl(normv, 4 * c + 2);
        const float n3 = __shfl(normv, 4 * c + 3);
        ushort4 w0, w1, w2, w3;
        w0.x = f2bf(a0.x * n0); w0.y = f2bf(a0.y * n0); w0.z = f2bf(a0.z * n0); w0.w = f2bf(a0.w * n0);
        w1.x = f2bf(a1.x * n1); w1.y = f2bf(a1.y * n1); w1.z = f2bf(a1.z * n1); w1.w = f2bf(a1.w * n1);
        w2.x = f2bf(a2.x * n2); w2.y = f2bf(a2.y * n2); w2.z = f2bf(a2.z * n2); w2.w = f2bf(a2.w * n2);
        w3.x = f2bf(a3.x * n3); w3.y = f2bf(a3.y * n3); w3.z = f2bf(a3.z * n3); w3.w = f2bf(a3.w * n3);
        *reinterpret_cast<ushort4*>(lbase + (size_t)(4 * c + 0) * LSTR + lane * 4) = w0;
        *reinterpret_cast<ushort4*>(lbase + (size_t)(4 * c + 1) * LSTR + lane * 4) = w1;
        *reinterpret_cast<ushort4*>(lbase + (size_t)(4 * c + 2) * LSTR + lane * 4) = w2;
        *reinterpret_cast<ushort4*>(lbase + (size_t)(4 * c + 3) * LSTR + lane * 4) = w3;
    }

    // ---- phase 2: GEMM (wave-private; compiler inserts lgkmcnt waits) ----
    const int kh = (lane >> 4) * 8;
    bf16x8 afr[8];
#pragma unroll
    for (int kk = 0; kk < 8; ++kk)
        afr[kk] = *reinterpret_cast<const bf16x8*>(lbase + (size_t)r16 * LSTR + kk * 32 + kh);

    f32x4 acc[16];
#pragma unroll
    for (int i = 0; i < 16; ++i) acc[i] = (f32x4){0.f, 0.f, 0.f, 0.f};

    const unsigned short* wb = Wt + (size_t)r16 * CH + kh;
#pragma unroll
    for (int kk = 0; kk < 8; ++kk) {
        const int k0 = kk * 32;
        bf16x8 b[16];
#pragma unroll
        for (int nt = 0; nt < 16; ++nt)
            b[nt] = *reinterpret_cast<const bf16x8*>(wb + (size_t)nt * 16 * CH + k0);
#pragma unroll
        for (int nt = 0; nt < 16; ++nt)
            acc[nt] = __builtin_amdgcn_mfma_f32_16x16x32_bf16(afr[kk], b[nt], acc[nt], 0, 0, 0);
    }

    const int crow = rowbase + (lane >> 4) * 4;
    const int ccol = lane & 15;
#pragma unroll
    for (int nt = 0; nt < 16; ++nt) {
        float* po = out + (size_t)crow * CH + nt * 16 + ccol;
#pragma unroll
        for (int r = 0; r < 4; ++r) po[(size_t)r * CH] = acc[nt][r];
    }
}

extern "C" void kernel_launch(void* const* d_in, const int* in_sizes, int n_in,
                              void* d_out, int out_size, void* d_ws, size_t ws_size,
                              hipStream_t stream) {
    const float* x = (const float*)d_in[0];
    const int* se = (const int*)d_in[1];
    const int* te = (const int*)d_in[2];
    const float* norm = (const float*)d_in[3];
    const float* W = (const float*)d_in[4];
    float* out = (float*)d_out;

    char* ws = (char*)d_ws;
    unsigned short* Wt = (unsigned short*)ws;            // 128 KB
    int* deg   = (int*)(ws + 131072);                    // 800 KB
    int* off   = (int*)(ws + 931072);                    // 800 KB
    int* cur   = (int*)(ws + 1731072);                   // 800 KB
    int* elist = (int*)(ws + 2531072);                   // 2.4 MB
    int* bsum  = (int*)(ws + 4931072);                   // 1 KB

    k_wt<<<CH, CH, 0, stream>>>(W, Wt);
    k_zero<<<(NN + 255) / 256, 256, 0, stream>>>(deg, NN);
    k_count<<<(NE + 255) / 256, 256, 0, stream>>>(te, deg);
    k_scanA<<<NBLK_SCAN, 256, 0, stream>>>(deg, off, bsum);
    k_scanB<<<1, 256, 0, stream>>>(bsum);
    k_scanC<<<NBLK_SCAN, 256, 0, stream>>>(off, bsum, cur);
    k_fill<<<(NE + 255) / 256, 256, 0, stream>>>(se, te, cur, elist);
    k_fused<<<NN / 64, 256, 0, stream>>>(x, off, deg, elist, norm, Wt, out);
}

// Round 5
// 343.502 us; speedup vs baseline: 6.7600x; 1.1794x over previous
//
#include <hip/hip_runtime.h>
#include <hip/hip_bf16.h>

#define NN 200000
#define NE 600000
#define CH 256
#define NBLK_SCAN 196   // ceil(200000/1024)

typedef short bf16x8 __attribute__((ext_vector_type(8)));
typedef float f32x4 __attribute__((ext_vector_type(4)));

__device__ __forceinline__ unsigned short f2bf(float f) {
    unsigned int u = __builtin_bit_cast(unsigned int, f);
    u = (u + 0x7FFFu + ((u >> 16) & 1u)) >> 16;
    return (unsigned short)u;
}

// K0: Wt[j][k] = bf16(W[k][j])
__global__ void k_wt(const float* __restrict__ W, unsigned short* __restrict__ Wt) {
    int j = blockIdx.x, k = threadIdx.x;
    Wt[j * CH + k] = f2bf(W[k * CH + j]);
}

__global__ void k_zero(int* __restrict__ p, int n) {
    int i = blockIdx.x * 256 + threadIdx.x;
    if (i < n) p[i] = 0;
}

__global__ void k_count(const int* __restrict__ te, int* __restrict__ deg) {
    int e = blockIdx.x * 256 + threadIdx.x;
    if (e < NE) atomicAdd(&deg[te[e]], 1);
}

__global__ __launch_bounds__(256) void k_scanA(const int* __restrict__ deg,
                                               int* __restrict__ off,
                                               int* __restrict__ bsum) {
    __shared__ int ts[256];
    int tid = threadIdx.x;
    int base = blockIdx.x * 1024 + tid * 4;
    int v[4];
#pragma unroll
    for (int j = 0; j < 4; ++j) {
        int idx = base + j;
        v[j] = (idx < NN) ? deg[idx] : 0;
    }
    int tsum = v[0] + v[1] + v[2] + v[3];
    ts[tid] = tsum;
    __syncthreads();
    int x = tsum;
    for (int ofs = 1; ofs < 256; ofs <<= 1) {
        int y = (tid >= ofs) ? ts[tid - ofs] : 0;
        __syncthreads();
        x += y;
        ts[tid] = x;
        __syncthreads();
    }
    int run = x - tsum;
#pragma unroll
    for (int j = 0; j < 4; ++j) {
        int idx = base + j;
        if (idx < NN) off[idx] = run;
        run += v[j];
    }
    if (tid == 255) bsum[blockIdx.x] = x;
}

__global__ __launch_bounds__(256) void k_scanB(int* __restrict__ bsum) {
    __shared__ int ts[256];
    int tid = threadIdx.x;
    int v = (tid < NBLK_SCAN) ? bsum[tid] : 0;
    ts[tid] = v;
    __syncthreads();
    int x = v;
    for (int ofs = 1; ofs < 256; ofs <<= 1) {
        int y = (tid >= ofs) ? ts[tid - ofs] : 0;
        __syncthreads();
        x += y;
        ts[tid] = x;
        __syncthreads();
    }
    if (tid < NBLK_SCAN) bsum[tid] = x - v;
}

__global__ __launch_bounds__(256) void k_scanC(int* __restrict__ off,
                                               const int* __restrict__ bsum,
                                               int* __restrict__ cur) {
    int tid = threadIdx.x;
    int base = blockIdx.x * 1024 + tid * 4;
    int bo = bsum[blockIdx.x];
#pragma unroll
    for (int j = 0; j < 4; ++j) {
        int idx = base + j;
        if (idx < NN) {
            int o = off[idx] + bo;
            off[idx] = o;
            cur[idx] = o;
        }
    }
}

__global__ void k_fill(const int* __restrict__ se, const int* __restrict__ te,
                       int* __restrict__ cur, int* __restrict__ elist) {
    int e = blockIdx.x * 256 + threadIdx.x;
    if (e < NE) {
        int t = te[e];
        int pos = atomicAdd(&cur[t], 1);
        elist[pos] = se[e];
    }
}

// gather: one wave per row; writes norm*(x[row]+sum edges) as f32,
// XOR-swizzled within the row (float4-group ^ (row&7)) for GEMM's LDS reads.
__global__ __launch_bounds__(256) void k_gather(const float* __restrict__ x,
                                                const int* __restrict__ off,
                                                const int* __restrict__ deg,
                                                const int* __restrict__ elist,
                                                const float* __restrict__ norm,
                                                float* __restrict__ out) {
    int wid = threadIdx.x >> 6;
    int lane = threadIdx.x & 63;
    int row = blockIdx.x * 4 + wid;
    if (row >= NN) return;
    int start = off[row];
    int d = deg[row];
    size_t loff = (size_t)lane * 4;
    float4 acc = *reinterpret_cast<const float4*>(x + (size_t)row * CH + loff);
    int e = 0;
    while (e < d) {
        int i0 = (e + 0 < d) ? elist[start + e + 0] : -1;
        int i1 = (e + 1 < d) ? elist[start + e + 1] : -1;
        int i2 = (e + 2 < d) ? elist[start + e + 2] : -1;
        int i3 = (e + 3 < d) ? elist[start + e + 3] : -1;
        int i4 = (e + 4 < d) ? elist[start + e + 4] : -1;
        int i5 = (e + 5 < d) ? elist[start + e + 5] : -1;
        int i6 = (e + 6 < d) ? elist[start + e + 6] : -1;
        int i7 = (e + 7 < d) ? elist[start + e + 7] : -1;
#define GACC(ii) if (ii >= 0) { \
            float4 v = *reinterpret_cast<const float4*>(x + (size_t)ii * CH + loff); \
            acc.x += v.x; acc.y += v.y; acc.z += v.z; acc.w += v.w; }
        GACC(i0) GACC(i1) GACC(i2) GACC(i3) GACC(i4) GACC(i5) GACC(i6) GACC(i7)
#undef GACC
        e += 8;
    }
    float nv = norm[row];
    acc.x *= nv; acc.y *= nv; acc.z *= nv; acc.w *= nv;
    // swizzled store: float4-group (lane) -> group (lane ^ (row&7))
    int fo = (lane * 4) ^ ((row & 7) << 2);
    *reinterpret_cast<float4*>(out + (size_t)row * CH + fo) = acc;
}

// GEMM: out = A @ W in-place; A (=norm*agg, f32, row-swizzled) staged per-block
// into LDS via global_load_lds(16B), then MFMA 16x16x32 with bf16 conversion
// in-register. Block: 64 rows x 256 cols; wave w owns cols [64w, 64w+64).
__global__ __launch_bounds__(256, 2) void k_gemm(const unsigned short* __restrict__ Wt,
                                                 float* __restrict__ out) {
    __shared__ float lds_a[64 * CH];   // 64 KB
    const int tid = threadIdx.x;
    const int wid = tid >> 6;
    const int lane = tid & 63;
    const int rb = blockIdx.x * 64;

    // stage the block's 64 rows (swizzled bytes copied verbatim)
    const float* gsrc = out + (size_t)rb * CH;
#pragma unroll
    for (int i = 0; i < 16; ++i) {
        int idx = (i * 256 + tid) * 4;  // float index, 16B per thread
        __builtin_amdgcn_global_load_lds(
            (const __attribute__((address_space(1))) void*)(gsrc + idx),
            (__attribute__((address_space(3))) void*)(&lds_a[idx]),
            16, 0, 0);
    }
    __syncthreads();   // compiler drains vmcnt before s_barrier

    const int r16 = lane & 15;
    const int q = lane >> 4;

    f32x4 acc[4][4];
#pragma unroll
    for (int m = 0; m < 4; ++m)
#pragma unroll
        for (int nt = 0; nt < 4; ++nt) acc[m][nt] = (f32x4){0.f, 0.f, 0.f, 0.f};

    const unsigned short* wb = Wt + (size_t)(wid * 64 + r16) * CH + q * 8;

#pragma unroll
    for (int kk = 0; kk < 8; ++kk) {
        const int c0 = kk * 32 + q * 8;
        bf16x8 b[4];
#pragma unroll
        for (int nt = 0; nt < 4; ++nt)
            b[nt] = *reinterpret_cast<const bf16x8*>(wb + (size_t)nt * 16 * CH + kk * 32);
        bf16x8 a[4];
#pragma unroll
        for (int m = 0; m < 4; ++m) {
            const int lr = m * 16 + r16;
            const int sw = (lr & 7) << 2;
            const float* lp = &lds_a[lr * CH];
            float4 lo = *reinterpret_cast<const float4*>(lp + (c0 ^ sw));
            float4 hi = *reinterpret_cast<const float4*>(lp + ((c0 + 4) ^ sw));
            a[m][0] = (short)f2bf(lo.x); a[m][1] = (short)f2bf(lo.y);
            a[m][2] = (short)f2bf(lo.z); a[m][3] = (short)f2bf(lo.w);
            a[m][4] = (short)f2bf(hi.x); a[m][5] = (short)f2bf(hi.y);
            a[m][6] = (short)f2bf(hi.z); a[m][7] = (short)f2bf(hi.w);
        }
#pragma unroll
        for (int m = 0; m < 4; ++m)
#pragma unroll
            for (int nt = 0; nt < 4; ++nt)
                acc[m][nt] = __builtin_amdgcn_mfma_f32_16x16x32_bf16(a[m], b[nt], acc[m][nt], 0, 0, 0);
    }

    // epilogue: wave wid -> cols [64*wid, +64), rows rb..rb+63
#pragma unroll
    for (int m = 0; m < 4; ++m) {
        const int crow = rb + m * 16 + q * 4;
#pragma unroll
        for (int nt = 0; nt < 4; ++nt) {
            float* po = out + (size_t)crow * CH + wid * 64 + nt * 16 + r16;
#pragma unroll
            for (int r = 0; r < 4; ++r) po[(size_t)r * CH] = acc[m][nt][r];
        }
    }
}

extern "C" void kernel_launch(void* const* d_in, const int* in_sizes, int n_in,
                              void* d_out, int out_size, void* d_ws, size_t ws_size,
                              hipStream_t stream) {
    const float* x = (const float*)d_in[0];
    const int* se = (const int*)d_in[1];
    const int* te = (const int*)d_in[2];
    const float* norm = (const float*)d_in[3];
    const float* W = (const float*)d_in[4];
    float* out = (float*)d_out;

    char* ws = (char*)d_ws;
    unsigned short* Wt = (unsigned short*)ws;            // 128 KB
    int* deg   = (int*)(ws + 131072);                    // 800 KB
    int* off   = (int*)(ws + 931072);                    // 800 KB
    int* cur   = (int*)(ws + 1731072);                   // 800 KB
    int* elist = (int*)(ws + 2531072);                   // 2.4 MB
    int* bsum  = (int*)(ws + 4931072);                   // 1 KB

    k_wt<<<CH, CH, 0, stream>>>(W, Wt);
    k_zero<<<(NN + 255) / 256, 256, 0, stream>>>(deg, NN);
    k_count<<<(NE + 255) / 256, 256, 0, stream>>>(te, deg);
    k_scanA<<<NBLK_SCAN, 256, 0, stream>>>(deg, off, bsum);
    k_scanB<<<1, 256, 0, stream>>>(bsum);
    k_scanC<<<NBLK_SCAN, 256, 0, stream>>>(off, bsum, cur);
    k_fill<<<(NE + 255) / 256, 256, 0, stream>>>(se, te, cur, elist);
    k_gather<<<(NN + 3) / 4, 256, 0, stream>>>(x, off, deg, elist, norm, out);
    k_gemm<<<NN / 64, 256, 0, stream>>>(Wt, out);
}

// Round 6
// 318.167 us; speedup vs baseline: 7.2982x; 1.0796x over previous
//
#include <hip/hip_runtime.h>
#include <hip/hip_bf16.h>

#define NN 200000
#define NE 600000
#define CH 256
#define NBLK_SCAN 196   // ceil(200000/1024)

typedef short bf16x8 __attribute__((ext_vector_type(8)));
typedef float f32x4 __attribute__((ext_vector_type(4)));
typedef unsigned short ushort8v __attribute__((ext_vector_type(8)));

__device__ __forceinline__ unsigned short f2bf(float f) {
    unsigned int u = __builtin_bit_cast(unsigned int, f);
    u = (u + 0x7FFFu + ((u >> 16) & 1u)) >> 16;
    return (unsigned short)u;
}
__device__ __forceinline__ float bf2f(unsigned short u) {
    unsigned int v = ((unsigned int)u) << 16;
    return __builtin_bit_cast(float, v);
}

// prep (fused): W transpose->bf16, degree count, optional x->bf16 convert
__global__ __launch_bounds__(256) void k_prep(const float* __restrict__ W,
                                              unsigned short* __restrict__ Wt,
                                              const float* __restrict__ x,
                                              unsigned short* __restrict__ xbf,
                                              const int* __restrict__ te,
                                              int* __restrict__ deg) {
    const int t = blockIdx.x * 256 + threadIdx.x;
    const int S = gridDim.x * 256;
    for (int e = t; e < NE; e += S) atomicAdd(&deg[te[e]], 1);
    for (int i = t; i < CH * CH; i += S) {
        int j = i >> 8, k = i & 255;
        Wt[j * CH + k] = f2bf(W[k * CH + j]);
    }
    if (xbf != nullptr) {
        const int NU = NN * CH / 8;  // 6.4M units of 8 floats
        for (int u = t; u < NU; u += S) {
            const float4 f0 = *reinterpret_cast<const float4*>(x + (size_t)u * 8);
            const float4 f1 = *reinterpret_cast<const float4*>(x + (size_t)u * 8 + 4);
            ushort8v w;
            w[0] = f2bf(f0.x); w[1] = f2bf(f0.y); w[2] = f2bf(f0.z); w[3] = f2bf(f0.w);
            w[4] = f2bf(f1.x); w[5] = f2bf(f1.y); w[6] = f2bf(f1.z); w[7] = f2bf(f1.w);
            *reinterpret_cast<ushort8v*>(xbf + (size_t)u * 8) = w;
        }
    }
}

__global__ __launch_bounds__(256) void k_scanA(const int* __restrict__ deg,
                                               int* __restrict__ off,
                                               int* __restrict__ bsum) {
    __shared__ int ts[256];
    int tid = threadIdx.x;
    int base = blockIdx.x * 1024 + tid * 4;
    int v[4];
#pragma unroll
    for (int j = 0; j < 4; ++j) {
        int idx = base + j;
        v[j] = (idx < NN) ? deg[idx] : 0;
    }
    int tsum = v[0] + v[1] + v[2] + v[3];
    ts[tid] = tsum;
    __syncthreads();
    int x = tsum;
    for (int ofs = 1; ofs < 256; ofs <<= 1) {
        int y = (tid >= ofs) ? ts[tid - ofs] : 0;
        __syncthreads();
        x += y;
        ts[tid] = x;
        __syncthreads();
    }
    int run = x - tsum;
#pragma unroll
    for (int j = 0; j < 4; ++j) {
        int idx = base + j;
        if (idx < NN) off[idx] = run;
        run += v[j];
    }
    if (tid == 255) bsum[blockIdx.x] = x;
}

__global__ __launch_bounds__(256) void k_scanB(int* __restrict__ bsum) {
    __shared__ int ts[256];
    int tid = threadIdx.x;
    int v = (tid < NBLK_SCAN) ? bsum[tid] : 0;
    ts[tid] = v;
    __syncthreads();
    int x = v;
    for (int ofs = 1; ofs < 256; ofs <<= 1) {
        int y = (tid >= ofs) ? ts[tid - ofs] : 0;
        __syncthreads();
        x += y;
        ts[tid] = x;
        __syncthreads();
    }
    if (tid < NBLK_SCAN) bsum[tid] = x - v;
}

__global__ __launch_bounds__(256) void k_scanC(int* __restrict__ off,
                                               const int* __restrict__ bsum,
                                               int* __restrict__ cur) {
    int tid = threadIdx.x;
    int base = blockIdx.x * 1024 + tid * 4;
    int bo = bsum[blockIdx.x];
#pragma unroll
    for (int j = 0; j < 4; ++j) {
        int idx = base + j;
        if (idx < NN) {
            int o = off[idx] + bo;
            off[idx] = o;
            cur[idx] = o;
        }
    }
}

__global__ void k_fill(const int* __restrict__ se, const int* __restrict__ te,
                       int* __restrict__ cur, int* __restrict__ elist) {
    int e = blockIdx.x * 256 + threadIdx.x;
    if (e < NE) {
        int t = te[e];
        int pos = atomicAdd(&cur[t], 1);
        elist[pos] = se[e];
    }
}

// ---------------- Path A (bf16 x, ws big enough) ----------------
// gather: one wave per row; aggbf[row] = bf16(norm*(xbf[row]+sum edges)),
// stored block-interleaved: row r -> ushort base (r>>6)*32768 + (r&63)*256,
// 16B-group-swizzled (group ^ (r&7)).
__global__ __launch_bounds__(256) void k_gather_a(const unsigned short* __restrict__ xbf,
                                                  const int* __restrict__ off,
                                                  const int* __restrict__ deg,
                                                  const int* __restrict__ elist,
                                                  const float* __restrict__ norm,
                                                  unsigned short* __restrict__ aggbf) {
    int wid = threadIdx.x >> 6;
    int lane = threadIdx.x & 63;
    int row = blockIdx.x * 4 + wid;
    if (row >= NN) return;
    int start = off[row];
    int d = deg[row];
    const int uo = lane * 4;
    ushort4 bv = *reinterpret_cast<const ushort4*>(xbf + (size_t)row * CH + uo);
    float ax = bf2f(bv.x), ay = bf2f(bv.y), az = bf2f(bv.z), aw = bf2f(bv.w);
    int e = 0;
    while (e < d) {
        int i0 = (e + 0 < d) ? elist[start + e + 0] : -1;
        int i1 = (e + 1 < d) ? elist[start + e + 1] : -1;
        int i2 = (e + 2 < d) ? elist[start + e + 2] : -1;
        int i3 = (e + 3 < d) ? elist[start + e + 3] : -1;
        int i4 = (e + 4 < d) ? elist[start + e + 4] : -1;
        int i5 = (e + 5 < d) ? elist[start + e + 5] : -1;
        int i6 = (e + 6 < d) ? elist[start + e + 6] : -1;
        int i7 = (e + 7 < d) ? elist[start + e + 7] : -1;
#define GACC(ii) if (ii >= 0) { \
            ushort4 v = *reinterpret_cast<const ushort4*>(xbf + (size_t)ii * CH + uo); \
            ax += bf2f(v.x); ay += bf2f(v.y); az += bf2f(v.z); aw += bf2f(v.w); }
        GACC(i0) GACC(i1) GACC(i2) GACC(i3) GACC(i4) GACC(i5) GACC(i6) GACC(i7)
#undef GACC
        e += 8;
    }
    float nv = norm[row];
    ushort4 w;
    w.x = f2bf(ax * nv); w.y = f2bf(ay * nv); w.z = f2bf(az * nv); w.w = f2bf(aw * nv);
    int g = lane >> 1;
    int gs = g ^ (row & 7);
    size_t dst = ((size_t)(row >> 6)) * 32768 + (size_t)(row & 63) * 256
               + (size_t)gs * 8 + (size_t)(lane & 1) * 4;
    *reinterpret_cast<ushort4*>(aggbf + dst) = w;
}

// GEMM path A: A is bf16, block-interleaved+swizzled in out's own region.
// Stage 32 KB via global_load_lds, ds_read_b128 straight into MFMA.
__global__ __launch_bounds__(256, 2) void k_gemm_a(const unsigned short* __restrict__ Wt,
                                                   float* __restrict__ out) {
    __shared__ unsigned short lds_a[64 * CH];  // 32 KB
    const int tid = threadIdx.x;
    const int wid = tid >> 6;
    const int lane = tid & 63;
    const int rb = blockIdx.x * 64;

    const unsigned short* gsrc = reinterpret_cast<const unsigned short*>(out)
                               + (size_t)blockIdx.x * 32768;
#pragma unroll
    for (int i = 0; i < 8; ++i) {
        int idx = i * 2048 + tid * 8;  // ushort index, 16B per thread
        __builtin_amdgcn_global_load_lds(
            (const __attribute__((address_space(1))) void*)(gsrc + idx),
            (__attribute__((address_space(3))) void*)(&lds_a[idx]),
            16, 0, 0);
    }
    __syncthreads();

    const int r16 = lane & 15;
    const int q = lane >> 4;

    f32x4 acc[4][4];
#pragma unroll
    for (int m = 0; m < 4; ++m)
#pragma unroll
        for (int nt = 0; nt < 4; ++nt) acc[m][nt] = (f32x4){0.f, 0.f, 0.f, 0.f};

    const unsigned short* wb = Wt + (size_t)(wid * 64 + r16) * CH + q * 8;

#pragma unroll
    for (int kk = 0; kk < 8; ++kk) {
        bf16x8 b[4];
#pragma unroll
        for (int nt = 0; nt < 4; ++nt)
            b[nt] = *reinterpret_cast<const bf16x8*>(wb + (size_t)nt * 16 * CH + kk * 32);
        bf16x8 a[4];
#pragma unroll
        for (int m = 0; m < 4; ++m) {
            const int lr = m * 16 + r16;
            const int idx = lr * CH + ((((kk * 4) + q) ^ (lr & 7)) << 3);
            a[m] = *reinterpret_cast<const bf16x8*>(&lds_a[idx]);
        }
#pragma unroll
        for (int m = 0; m < 4; ++m)
#pragma unroll
            for (int nt = 0; nt < 4; ++nt)
                acc[m][nt] = __builtin_amdgcn_mfma_f32_16x16x32_bf16(a[m], b[nt], acc[m][nt], 0, 0, 0);
    }

#pragma unroll
    for (int m = 0; m < 4; ++m) {
        const int crow = rb + m * 16 + q * 4;
#pragma unroll
        for (int nt = 0; nt < 4; ++nt) {
            float* po = out + (size_t)crow * CH + wid * 64 + nt * 16 + r16;
#pragma unroll
            for (int r = 0; r < 4; ++r) po[(size_t)r * CH] = acc[m][nt][r];
        }
    }
}

// ---------------- Path B (fallback, f32 handoff in-place) ----------------
__global__ __launch_bounds__(256) void k_gather_b(const float* __restrict__ x,
                                                  const int* __restrict__ off,
                                                  const int* __restrict__ deg,
                                                  const int* __restrict__ elist,
                                                  const float* __restrict__ norm,
                                                  float* __restrict__ out) {
    int wid = threadIdx.x >> 6;
    int lane = threadIdx.x & 63;
    int row = blockIdx.x * 4 + wid;
    if (row >= NN) return;
    int start = off[row];
    int d = deg[row];
    size_t loff = (size_t)lane * 4;
    float4 acc = *reinterpret_cast<const float4*>(x + (size_t)row * CH + loff);
    int e = 0;
    while (e < d) {
        int i0 = (e + 0 < d) ? elist[start + e + 0] : -1;
        int i1 = (e + 1 < d) ? elist[start + e + 1] : -1;
        int i2 = (e + 2 < d) ? elist[start + e + 2] : -1;
        int i3 = (e + 3 < d) ? elist[start + e + 3] : -1;
        int i4 = (e + 4 < d) ? elist[start + e + 4] : -1;
        int i5 = (e + 5 < d) ? elist[start + e + 5] : -1;
        int i6 = (e + 6 < d) ? elist[start + e + 6] : -1;
        int i7 = (e + 7 < d) ? elist[start + e + 7] : -1;
#define GACC(ii) if (ii >= 0) { \
            float4 v = *reinterpret_cast<const float4*>(x + (size_t)ii * CH + loff); \
            acc.x += v.x; acc.y += v.y; acc.z += v.z; acc.w += v.w; }
        GACC(i0) GACC(i1) GACC(i2) GACC(i3) GACC(i4) GACC(i5) GACC(i6) GACC(i7)
#undef GACC
        e += 8;
    }
    float nv = norm[row];
    acc.x *= nv; acc.y *= nv; acc.z *= nv; acc.w *= nv;
    int fo = (lane * 4) ^ ((row & 7) << 2);
    *reinterpret_cast<float4*>(out + (size_t)row * CH + fo) = acc;
}

__global__ __launch_bounds__(256, 2) void k_gemm_b(const unsigned short* __restrict__ Wt,
                                                   float* __restrict__ out) {
    __shared__ float lds_a[64 * CH];  // 64 KB
    const int tid = threadIdx.x;
    const int wid = tid >> 6;
    const int lane = tid & 63;
    const int rb = blockIdx.x * 64;

    const float* gsrc = out + (size_t)rb * CH;
#pragma unroll
    for (int i = 0; i < 16; ++i) {
        int idx = (i * 256 + tid) * 4;
        __builtin_amdgcn_global_load_lds(
            (const __attribute__((address_space(1))) void*)(gsrc + idx),
            (__attribute__((address_space(3))) void*)(&lds_a[idx]),
            16, 0, 0);
    }
    __syncthreads();

    const int r16 = lane & 15;
    const int q = lane >> 4;

    f32x4 acc[4][4];
#pragma unroll
    for (int m = 0; m < 4; ++m)
#pragma unroll
        for (int nt = 0; nt < 4; ++nt) acc[m][nt] = (f32x4){0.f, 0.f, 0.f, 0.f};

    const unsigned short* wb = Wt + (size_t)(wid * 64 + r16) * CH + q * 8;

#pragma unroll
    for (int kk = 0; kk < 8; ++kk) {
        const int c0 = kk * 32 + q * 8;
        bf16x8 b[4];
#pragma unroll
        for (int nt = 0; nt < 4; ++nt)
            b[nt] = *reinterpret_cast<const bf16x8*>(wb + (size_t)nt * 16 * CH + kk * 32);
        bf16x8 a[4];
#pragma unroll
        for (int m = 0; m < 4; ++m) {
            const int lr = m * 16 + r16;
            const int sw = (lr & 7) << 2;
            const float* lp = &lds_a[lr * CH];
            float4 lo = *reinterpret_cast<const float4*>(lp + (c0 ^ sw));
            float4 hi = *reinterpret_cast<const float4*>(lp + ((c0 + 4) ^ sw));
            a[m][0] = (short)f2bf(lo.x); a[m][1] = (short)f2bf(lo.y);
            a[m][2] = (short)f2bf(lo.z); a[m][3] = (short)f2bf(lo.w);
            a[m][4] = (short)f2bf(hi.x); a[m][5] = (short)f2bf(hi.y);
            a[m][6] = (short)f2bf(hi.z); a[m][7] = (short)f2bf(hi.w);
        }
#pragma unroll
        for (int m = 0; m < 4; ++m)
#pragma unroll
            for (int nt = 0; nt < 4; ++nt)
                acc[m][nt] = __builtin_amdgcn_mfma_f32_16x16x32_bf16(a[m], b[nt], acc[m][nt], 0, 0, 0);
    }

#pragma unroll
    for (int m = 0; m < 4; ++m) {
        const int crow = rb + m * 16 + q * 4;
#pragma unroll
        for (int nt = 0; nt < 4; ++nt) {
            float* po = out + (size_t)crow * CH + wid * 64 + nt * 16 + r16;
#pragma unroll
            for (int r = 0; r < 4; ++r) po[(size_t)r * CH] = acc[m][nt][r];
        }
    }
}

extern "C" void kernel_launch(void* const* d_in, const int* in_sizes, int n_in,
                              void* d_out, int out_size, void* d_ws, size_t ws_size,
                              hipStream_t stream) {
    const float* x = (const float*)d_in[0];
    const int* se = (const int*)d_in[1];
    const int* te = (const int*)d_in[2];
    const float* norm = (const float*)d_in[3];
    const float* W = (const float*)d_in[4];
    float* out = (float*)d_out;

    char* ws = (char*)d_ws;
    unsigned short* Wt = (unsigned short*)ws;             // 128 KB
    int* deg   = (int*)(ws + 131072);                     // 800 KB
    int* off   = (int*)(ws + 931072);                     // 800 KB
    int* cur   = (int*)(ws + 1731072);                    // 800 KB
    int* elist = (int*)(ws + 2531072);                    // 2.4 MB
    int* bsum  = (int*)(ws + 4931072);                    // 1 KB
    const size_t XBF_OFF = 4932096;
    const size_t NEED = XBF_OFF + (size_t)NN * CH * 2;    // ~107.3 MB
    const bool big = (ws_size >= NEED);
    unsigned short* xbf = big ? (unsigned short*)(ws + XBF_OFF) : nullptr;

    hipMemsetAsync(deg, 0, NN * sizeof(int), stream);
    k_prep<<<1024, 256, 0, stream>>>(W, Wt, x, xbf, te, deg);
    k_scanA<<<NBLK_SCAN, 256, 0, stream>>>(deg, off, bsum);
    k_scanB<<<1, 256, 0, stream>>>(bsum);
    k_scanC<<<NBLK_SCAN, 256, 0, stream>>>(off, bsum, cur);
    k_fill<<<(NE + 255) / 256, 256, 0, stream>>>(se, te, cur, elist);
    if (big) {
        k_gather_a<<<NN / 4, 256, 0, stream>>>(xbf, off, deg, elist, norm,
                                               (unsigned short*)out);
        k_gemm_a<<<NN / 64, 256, 0, stream>>>(Wt, out);
    } else {
        k_gather_b<<<NN / 4, 256, 0, stream>>>(x, off, deg, elist, norm, out);
        k_gemm_b<<<NN / 64, 256, 0, stream>>>(Wt, out);
    }
}

// Round 7
// 300.814 us; speedup vs baseline: 7.7193x; 1.0577x over previous
//
#include <hip/hip_runtime.h>
#include <hip/hip_bf16.h>

#define NN 200000
#define NE 600000
#define CH 256
#define NBLK_SCAN 196   // ceil(200000/1024)

typedef short bf16x8 __attribute__((ext_vector_type(8)));
typedef float f32x4 __attribute__((ext_vector_type(4)));
typedef unsigned short ushort8v __attribute__((ext_vector_type(8)));

__device__ __forceinline__ unsigned short f2bf(float f) {
    unsigned int u = __builtin_bit_cast(unsigned int, f);
    u = (u + 0x7FFFu + ((u >> 16) & 1u)) >> 16;
    return (unsigned short)u;
}
__device__ __forceinline__ float bf2f(unsigned short u) {
    unsigned int v = ((unsigned int)u) << 16;
    return __builtin_bit_cast(float, v);
}

// prep (fused): W transpose->bf16, degree count, optional x->bf16 convert
__global__ __launch_bounds__(256) void k_prep(const float* __restrict__ W,
                                              unsigned short* __restrict__ Wt,
                                              const float* __restrict__ x,
                                              unsigned short* __restrict__ xbf,
                                              const int* __restrict__ te,
                                              int* __restrict__ deg) {
    const int t = blockIdx.x * 256 + threadIdx.x;
    const int S = gridDim.x * 256;
    for (int e = t; e < NE; e += S) atomicAdd(&deg[te[e]], 1);
    for (int i = t; i < CH * CH; i += S) {
        int j = i >> 8, k = i & 255;
        Wt[j * CH + k] = f2bf(W[k * CH + j]);
    }
    if (xbf != nullptr) {
        const int NU = NN * CH / 8;
        for (int u = t; u < NU; u += S) {
            const float4 f0 = *reinterpret_cast<const float4*>(x + (size_t)u * 8);
            const float4 f1 = *reinterpret_cast<const float4*>(x + (size_t)u * 8 + 4);
            ushort8v w;
            w[0] = f2bf(f0.x); w[1] = f2bf(f0.y); w[2] = f2bf(f0.z); w[3] = f2bf(f0.w);
            w[4] = f2bf(f1.x); w[5] = f2bf(f1.y); w[6] = f2bf(f1.z); w[7] = f2bf(f1.w);
            *reinterpret_cast<ushort8v*>(xbf + (size_t)u * 8) = w;
        }
    }
}

__global__ __launch_bounds__(256) void k_scanA(const int* __restrict__ deg,
                                               int* __restrict__ off,
                                               int* __restrict__ bsum) {
    __shared__ int ts[256];
    int tid = threadIdx.x;
    int base = blockIdx.x * 1024 + tid * 4;
    int v[4];
#pragma unroll
    for (int j = 0; j < 4; ++j) {
        int idx = base + j;
        v[j] = (idx < NN) ? deg[idx] : 0;
    }
    int tsum = v[0] + v[1] + v[2] + v[3];
    ts[tid] = tsum;
    __syncthreads();
    int x = tsum;
    for (int ofs = 1; ofs < 256; ofs <<= 1) {
        int y = (tid >= ofs) ? ts[tid - ofs] : 0;
        __syncthreads();
        x += y;
        ts[tid] = x;
        __syncthreads();
    }
    int run = x - tsum;
#pragma unroll
    for (int j = 0; j < 4; ++j) {
        int idx = base + j;
        if (idx < NN) off[idx] = run;
        run += v[j];
    }
    if (tid == 255) bsum[blockIdx.x] = x;
}

__global__ __launch_bounds__(256) void k_scanB(int* __restrict__ bsum) {
    __shared__ int ts[256];
    int tid = threadIdx.x;
    int v = (tid < NBLK_SCAN) ? bsum[tid] : 0;
    ts[tid] = v;
    __syncthreads();
    int x = v;
    for (int ofs = 1; ofs < 256; ofs <<= 1) {
        int y = (tid >= ofs) ? ts[tid - ofs] : 0;
        __syncthreads();
        x += y;
        ts[tid] = x;
        __syncthreads();
    }
    if (tid < NBLK_SCAN) bsum[tid] = x - v;
}

__global__ __launch_bounds__(256) void k_scanC(int* __restrict__ off,
                                               const int* __restrict__ bsum,
                                               int* __restrict__ cur) {
    int tid = threadIdx.x;
    int base = blockIdx.x * 1024 + tid * 4;
    int bo = bsum[blockIdx.x];
#pragma unroll
    for (int j = 0; j < 4; ++j) {
        int idx = base + j;
        if (idx < NN) {
            int o = off[idx] + bo;
            off[idx] = o;
            cur[idx] = o;
        }
    }
}

__global__ void k_fill(const int* __restrict__ se, const int* __restrict__ te,
                       int* __restrict__ cur, int* __restrict__ elist) {
    int e = blockIdx.x * 256 + threadIdx.x;
    if (e < NE) {
        int t = te[e];
        int pos = atomicAdd(&cur[t], 1);
        elist[pos] = se[e];
    }
}

// ---------------- Path A: fused gather + GEMM ----------------
// Block: 64 rows. Phase 1: wave wid gathers rows [wid*16, wid*16+16) into a
// swizzled bf16 LDS tile (base rows prefetched, unroll-8 edge loop).
// Phase 2: 16x16x32 MFMA, A straight from LDS, B (Wt) from L2; norm applied
// exactly in the f32 epilogue (diag(n)*(A@W) == (diag(n)*A)@W).
__global__ __launch_bounds__(256, 4) void k_fgg(const unsigned short* __restrict__ xbf,
                                                const int* __restrict__ off,
                                                const int* __restrict__ deg,
                                                const int* __restrict__ elist,
                                                const float* __restrict__ norm,
                                                const unsigned short* __restrict__ Wt,
                                                float* __restrict__ out) {
    __shared__ unsigned short lds_a[64 * CH];  // 32 KB
    const int tid = threadIdx.x;
    const int wid = tid >> 6;
    const int lane = tid & 63;
    const int rb = blockIdx.x * 64;
    const int rowbase = rb + wid * 16;
    const int r16 = lane & 15;
    const int q = lane >> 4;

    // per-wave row metadata (lane r holds row rowbase+r for r<16)
    const int offv = off[rowbase + r16];
    const int degv = deg[rowbase + r16];
    const float nv = norm[rb + lane];     // wave covers 64 norms? no: block rows rb..rb+63
    const int uo = lane * 4;              // ushort offset within row (8B/lane)

    // prefetch all 16 base rows (independent loads in flight)
    ushort4 base[16];
#pragma unroll
    for (int r = 0; r < 16; ++r)
        base[r] = *reinterpret_cast<const ushort4*>(xbf + (size_t)(rowbase + r) * CH + uo);

    unsigned short* lb = lds_a + wid * 16 * CH;
#pragma unroll
    for (int r = 0; r < 16; ++r) {
        const int start = __shfl(offv, r);
        const int d = __shfl(degv, r);
        float ax = bf2f(base[r].x), ay = bf2f(base[r].y);
        float az = bf2f(base[r].z), aw = bf2f(base[r].w);
        int e = 0;
        while (e < d) {
            int i0 = (e + 0 < d) ? elist[start + e + 0] : -1;
            int i1 = (e + 1 < d) ? elist[start + e + 1] : -1;
            int i2 = (e + 2 < d) ? elist[start + e + 2] : -1;
            int i3 = (e + 3 < d) ? elist[start + e + 3] : -1;
            int i4 = (e + 4 < d) ? elist[start + e + 4] : -1;
            int i5 = (e + 5 < d) ? elist[start + e + 5] : -1;
            int i6 = (e + 6 < d) ? elist[start + e + 6] : -1;
            int i7 = (e + 7 < d) ? elist[start + e + 7] : -1;
#define GACC(ii) if (ii >= 0) { \
            ushort4 v = *reinterpret_cast<const ushort4*>(xbf + (size_t)ii * CH + uo); \
            ax += bf2f(v.x); ay += bf2f(v.y); az += bf2f(v.z); aw += bf2f(v.w); }
            GACC(i0) GACC(i1) GACC(i2) GACC(i3) GACC(i4) GACC(i5) GACC(i6) GACC(i7)
#undef GACC
            e += 8;
        }
        ushort4 w;
        w.x = f2bf(ax); w.y = f2bf(ay); w.z = f2bf(az); w.w = f2bf(aw);
        // swizzled LDS store: 16B-group g -> g ^ (localrow & 7); localrow = wid*16+r, &7 == r&7
        const int g = lane >> 1;
        const int gs = g ^ (r & 7);
        *reinterpret_cast<ushort4*>(lb + r * CH + gs * 8 + (lane & 1) * 4) = w;
    }
    __syncthreads();

    f32x4 acc[4][4];
#pragma unroll
    for (int m = 0; m < 4; ++m)
#pragma unroll
        for (int nt = 0; nt < 4; ++nt) acc[m][nt] = (f32x4){0.f, 0.f, 0.f, 0.f};

    const unsigned short* wb = Wt + (size_t)(wid * 64 + r16) * CH + q * 8;

#pragma unroll
    for (int kk = 0; kk < 8; ++kk) {
        bf16x8 b[4];
#pragma unroll
        for (int nt = 0; nt < 4; ++nt)
            b[nt] = *reinterpret_cast<const bf16x8*>(wb + (size_t)nt * 16 * CH + kk * 32);
        bf16x8 a[4];
#pragma unroll
        for (int m = 0; m < 4; ++m) {
            const int lr = m * 16 + r16;
            const int idx = lr * CH + ((((kk * 4) + q) ^ (lr & 7)) << 3);
            a[m] = *reinterpret_cast<const bf16x8*>(&lds_a[idx]);
        }
#pragma unroll
        for (int m = 0; m < 4; ++m)
#pragma unroll
            for (int nt = 0; nt < 4; ++nt)
                acc[m][nt] = __builtin_amdgcn_mfma_f32_16x16x32_bf16(a[m], b[nt], acc[m][nt], 0, 0, 0);
    }

    // epilogue: exact f32 row-scale by norm, then store
#pragma unroll
    for (int m = 0; m < 4; ++m) {
        const int crow = rb + m * 16 + q * 4;
#pragma unroll
        for (int nt = 0; nt < 4; ++nt) {
            float* po = out + (size_t)crow * CH + wid * 64 + nt * 16 + r16;
#pragma unroll
            for (int r = 0; r < 4; ++r) {
                const float nj = __shfl(nv, m * 16 + q * 4 + r);
                po[(size_t)r * CH] = acc[m][nt][r] * nj;
            }
        }
    }
}

// ---------------- Path B (fallback, f32 handoff in-place) ----------------
__global__ __launch_bounds__(256) void k_gather_b(const float* __restrict__ x,
                                                  const int* __restrict__ off,
                                                  const int* __restrict__ deg,
                                                  const int* __restrict__ elist,
                                                  const float* __restrict__ norm,
                                                  float* __restrict__ out) {
    int wid = threadIdx.x >> 6;
    int lane = threadIdx.x & 63;
    int row = blockIdx.x * 4 + wid;
    if (row >= NN) return;
    int start = off[row];
    int d = deg[row];
    size_t loff = (size_t)lane * 4;
    float4 acc = *reinterpret_cast<const float4*>(x + (size_t)row * CH + loff);
    int e = 0;
    while (e < d) {
        int i0 = (e + 0 < d) ? elist[start + e + 0] : -1;
        int i1 = (e + 1 < d) ? elist[start + e + 1] : -1;
        int i2 = (e + 2 < d) ? elist[start + e + 2] : -1;
        int i3 = (e + 3 < d) ? elist[start + e + 3] : -1;
        int i4 = (e + 4 < d) ? elist[start + e + 4] : -1;
        int i5 = (e + 5 < d) ? elist[start + e + 5] : -1;
        int i6 = (e + 6 < d) ? elist[start + e + 6] : -1;
        int i7 = (e + 7 < d) ? elist[start + e + 7] : -1;
#define GACC(ii) if (ii >= 0) { \
            float4 v = *reinterpret_cast<const float4*>(x + (size_t)ii * CH + loff); \
            acc.x += v.x; acc.y += v.y; acc.z += v.z; acc.w += v.w; }
        GACC(i0) GACC(i1) GACC(i2) GACC(i3) GACC(i4) GACC(i5) GACC(i6) GACC(i7)
#undef GACC
        e += 8;
    }
    float nvv = norm[row];
    acc.x *= nvv; acc.y *= nvv; acc.z *= nvv; acc.w *= nvv;
    int fo = (lane * 4) ^ ((row & 7) << 2);
    *reinterpret_cast<float4*>(out + (size_t)row * CH + fo) = acc;
}

__global__ __launch_bounds__(256, 2) void k_gemm_b(const unsigned short* __restrict__ Wt,
                                                   float* __restrict__ out) {
    __shared__ float lds_a[64 * CH];
    const int tid = threadIdx.x;
    const int wid = tid >> 6;
    const int lane = tid & 63;
    const int rb = blockIdx.x * 64;

    const float* gsrc = out + (size_t)rb * CH;
#pragma unroll
    for (int i = 0; i < 16; ++i) {
        int idx = (i * 256 + tid) * 4;
        __builtin_amdgcn_global_load_lds(
            (const __attribute__((address_space(1))) void*)(gsrc + idx),
            (__attribute__((address_space(3))) void*)(&lds_a[idx]),
            16, 0, 0);
    }
    __syncthreads();

    const int r16 = lane & 15;
    const int q = lane >> 4;

    f32x4 acc[4][4];
#pragma unroll
    for (int m = 0; m < 4; ++m)
#pragma unroll
        for (int nt = 0; nt < 4; ++nt) acc[m][nt] = (f32x4){0.f, 0.f, 0.f, 0.f};

    const unsigned short* wb = Wt + (size_t)(wid * 64 + r16) * CH + q * 8;

#pragma unroll
    for (int kk = 0; kk < 8; ++kk) {
        const int c0 = kk * 32 + q * 8;
        bf16x8 b[4];
#pragma unroll
        for (int nt = 0; nt < 4; ++nt)
            b[nt] = *reinterpret_cast<const bf16x8*>(wb + (size_t)nt * 16 * CH + kk * 32);
        bf16x8 a[4];
#pragma unroll
        for (int m = 0; m < 4; ++m) {
            const int lr = m * 16 + r16;
            const int sw = (lr & 7) << 2;
            const float* lp = &lds_a[lr * CH];
            float4 lo = *reinterpret_cast<const float4*>(lp + (c0 ^ sw));
            float4 hi = *reinterpret_cast<const float4*>(lp + ((c0 + 4) ^ sw));
            a[m][0] = (short)f2bf(lo.x); a[m][1] = (short)f2bf(lo.y);
            a[m][2] = (short)f2bf(lo.z); a[m][3] = (short)f2bf(lo.w);
            a[m][4] = (short)f2bf(hi.x); a[m][5] = (short)f2bf(hi.y);
            a[m][6] = (short)f2bf(hi.z); a[m][7] = (short)f2bf(hi.w);
        }
#pragma unroll
        for (int m = 0; m < 4; ++m)
#pragma unroll
            for (int nt = 0; nt < 4; ++nt)
                acc[m][nt] = __builtin_amdgcn_mfma_f32_16x16x32_bf16(a[m], b[nt], acc[m][nt], 0, 0, 0);
    }

#pragma unroll
    for (int m = 0; m < 4; ++m) {
        const int crow = rb + m * 16 + q * 4;
#pragma unroll
        for (int nt = 0; nt < 4; ++nt) {
            float* po = out + (size_t)crow * CH + wid * 64 + nt * 16 + r16;
#pragma unroll
            for (int r = 0; r < 4; ++r) po[(size_t)r * CH] = acc[m][nt][r];
        }
    }
}

extern "C" void kernel_launch(void* const* d_in, const int* in_sizes, int n_in,
                              void* d_out, int out_size, void* d_ws, size_t ws_size,
                              hipStream_t stream) {
    const float* x = (const float*)d_in[0];
    const int* se = (const int*)d_in[1];
    const int* te = (const int*)d_in[2];
    const float* norm = (const float*)d_in[3];
    const float* W = (const float*)d_in[4];
    float* out = (float*)d_out;

    char* ws = (char*)d_ws;
    unsigned short* Wt = (unsigned short*)ws;             // 128 KB
    int* deg   = (int*)(ws + 131072);                     // 800 KB
    int* off   = (int*)(ws + 931072);                     // 800 KB
    int* cur   = (int*)(ws + 1731072);                    // 800 KB
    int* elist = (int*)(ws + 2531072);                    // 2.4 MB
    int* bsum  = (int*)(ws + 4931072);                    // 1 KB
    const size_t XBF_OFF = 4932096;
    const size_t NEED = XBF_OFF + (size_t)NN * CH * 2;    // ~107.3 MB
    const bool big = (ws_size >= NEED);
    unsigned short* xbf = big ? (unsigned short*)(ws + XBF_OFF) : nullptr;

    hipMemsetAsync(deg, 0, NN * sizeof(int), stream);
    k_prep<<<1024, 256, 0, stream>>>(W, Wt, x, xbf, te, deg);
    k_scanA<<<NBLK_SCAN, 256, 0, stream>>>(deg, off, bsum);
    k_scanB<<<1, 256, 0, stream>>>(bsum);
    k_scanC<<<NBLK_SCAN, 256, 0, stream>>>(off, bsum, cur);
    k_fill<<<(NE + 255) / 256, 256, 0, stream>>>(se, te, cur, elist);
    if (big) {
        k_fgg<<<NN / 64, 256, 0, stream>>>(xbf, off, deg, elist, norm, Wt, out);
    } else {
        k_gather_b<<<NN / 4, 256, 0, stream>>>(x, off, deg, elist, norm, out);
        k_gemm_b<<<NN / 64, 256, 0, stream>>>(Wt, out);
    }
}

// Round 8
// 284.800 us; speedup vs baseline: 8.1533x; 1.0562x over previous
//
#include <hip/hip_runtime.h>
#include <hip/hip_bf16.h>

#define NN 200000
#define NE 600000
#define CH 256
#define NBLK_SCAN 196   // ceil(200000/1024)
#define CAP 256         // per-wave staged edge-index capacity

typedef short bf16x8 __attribute__((ext_vector_type(8)));
typedef float f32x4 __attribute__((ext_vector_type(4)));

__device__ __forceinline__ unsigned short f2bf(float f) {
    unsigned int u = __builtin_bit_cast(unsigned int, f);
    u = (u + 0x7FFFu + ((u >> 16) & 1u)) >> 16;
    return (unsigned short)u;
}

// prep (fused): W transpose->bf16 + degree count
__global__ __launch_bounds__(256) void k_prep(const float* __restrict__ W,
                                              unsigned short* __restrict__ Wt,
                                              const int* __restrict__ te,
                                              int* __restrict__ deg) {
    const int t = blockIdx.x * 256 + threadIdx.x;
    const int S = gridDim.x * 256;
    for (int e = t; e < NE; e += S) atomicAdd(&deg[te[e]], 1);
    for (int i = t; i < CH * CH; i += S) {
        int j = i >> 8, k = i & 255;
        Wt[j * CH + k] = f2bf(W[k * CH + j]);
    }
}

__global__ __launch_bounds__(256) void k_scanA(const int* __restrict__ deg,
                                               int* __restrict__ off,
                                               int* __restrict__ bsum) {
    __shared__ int ts[256];
    int tid = threadIdx.x;
    int base = blockIdx.x * 1024 + tid * 4;
    int v[4];
#pragma unroll
    for (int j = 0; j < 4; ++j) {
        int idx = base + j;
        v[j] = (idx < NN) ? deg[idx] : 0;
    }
    int tsum = v[0] + v[1] + v[2] + v[3];
    ts[tid] = tsum;
    __syncthreads();
    int x = tsum;
    for (int ofs = 1; ofs < 256; ofs <<= 1) {
        int y = (tid >= ofs) ? ts[tid - ofs] : 0;
        __syncthreads();
        x += y;
        ts[tid] = x;
        __syncthreads();
    }
    int run = x - tsum;
#pragma unroll
    for (int j = 0; j < 4; ++j) {
        int idx = base + j;
        if (idx < NN) off[idx] = run;
        run += v[j];
    }
    if (tid == 255) bsum[blockIdx.x] = x;
}

__global__ __launch_bounds__(256) void k_scanB(int* __restrict__ bsum) {
    __shared__ int ts[256];
    int tid = threadIdx.x;
    int v = (tid < NBLK_SCAN) ? bsum[tid] : 0;
    ts[tid] = v;
    __syncthreads();
    int x = v;
    for (int ofs = 1; ofs < 256; ofs <<= 1) {
        int y = (tid >= ofs) ? ts[tid - ofs] : 0;
        __syncthreads();
        x += y;
        ts[tid] = x;
        __syncthreads();
    }
    if (tid < NBLK_SCAN) bsum[tid] = x - v;
}

__global__ __launch_bounds__(256) void k_scanC(int* __restrict__ off,
                                               const int* __restrict__ bsum,
                                               int* __restrict__ cur) {
    int tid = threadIdx.x;
    int base = blockIdx.x * 1024 + tid * 4;
    int bo = bsum[blockIdx.x];
#pragma unroll
    for (int j = 0; j < 4; ++j) {
        int idx = base + j;
        if (idx < NN) {
            int o = off[idx] + bo;
            off[idx] = o;
            cur[idx] = o;
        }
    }
}

__global__ void k_fill(const int* __restrict__ se, const int* __restrict__ te,
                       int* __restrict__ cur, int* __restrict__ elist) {
    int e = blockIdx.x * 256 + threadIdx.x;
    if (e < NE) {
        int t = te[e];
        int pos = atomicAdd(&cur[t], 1);
        elist[pos] = se[e];
    }
}

// Fused gather + GEMM.
// Phase 1: wave wid owns rows [wid*16, wid*16+16). Stage the wave's contiguous
// CSR index range into LDS, then e-outer/row-inner unrolled gather (up to 32
// independent f32x4 gathers in flight). Convert+swizzle-store bf16 tile to LDS.
// Phase 2: 16x16x32 MFMA, A from LDS (swizzled, conflict-light), B (Wt) from L2.
// norm applied exactly in f32 epilogue.
__global__ __launch_bounds__(256, 4) void k_fgg(const float* __restrict__ x,
                                                const int* __restrict__ off,
                                                const int* __restrict__ deg,
                                                const int* __restrict__ elist,
                                                const float* __restrict__ norm,
                                                const unsigned short* __restrict__ Wt,
                                                float* __restrict__ out) {
    __shared__ unsigned short lds_a[64 * CH];  // 32 KB
    __shared__ int lds_idx[4][CAP];            // 4 KB
    const int tid = threadIdx.x;
    const int wid = tid >> 6;
    const int lane = tid & 63;
    const int rb = blockIdx.x * 64;
    const int rowbase = rb + wid * 16;
    const int r16 = lane & 15;
    const int q = lane >> 4;
    const int fo4 = lane * 4;          // float offset within row (16B/lane)

    const int offv = off[rowbase + r16];
    const int degv = deg[rowbase + r16];
    const float nv = norm[rb + lane];

    // wave's contiguous edge range
    const int estart = __shfl(offv, 0);
    const int eend = __shfl(offv, 15) + __shfl(degv, 15);
    const int cnt = eend - estart;

    // stage indices into LDS (coalesced; usually one iteration)
    if (cnt <= CAP) {
        for (int i = lane; i < cnt; i += 64)
            lds_idx[wid][i] = elist[estart + i];
    }

    // base rows -> accumulators (16 independent coalesced loads)
    float4 acc[16];
#pragma unroll
    for (int r = 0; r < 16; ++r)
        acc[r] = *reinterpret_cast<const float4*>(x + (size_t)(rowbase + r) * CH + fo4);

    int drs[16], srs[16];
#pragma unroll
    for (int r = 0; r < 16; ++r) {
        drs[r] = __shfl(degv, r);
        srs[r] = __shfl(offv, r) - estart;
    }
    int md = 0;
#pragma unroll
    for (int r = 0; r < 16; ++r) md = max(md, drs[r]);

#define EDGE_LOOP(IDX)                                                                   \
    for (int e = 0; e < md; e += 2) {                                                    \
        _Pragma("unroll")                                                                \
        for (int r = 0; r < 16; ++r) {                                                   \
            if (e < drs[r]) {                                                            \
                const int p0 = srs[r] + e;                                               \
                const int i0 = IDX(p0);                                                  \
                float4 v0 = *reinterpret_cast<const float4*>(x + (size_t)i0 * CH + fo4); \
                acc[r].x += v0.x; acc[r].y += v0.y;                                      \
                acc[r].z += v0.z; acc[r].w += v0.w;                                      \
                if (e + 1 < drs[r]) {                                                    \
                    const int i1 = IDX(p0 + 1);                                          \
                    float4 v1 = *reinterpret_cast<const float4*>(x + (size_t)i1 * CH + fo4); \
                    acc[r].x += v1.x; acc[r].y += v1.y;                                  \
                    acc[r].z += v1.z; acc[r].w += v1.w;                                  \
                }                                                                        \
            }                                                                            \
        }                                                                                \
    }
#define LDSIDX(p) lds_idx[wid][p]
#define GLOBIDX(p) elist[estart + (p)]
    if (cnt <= CAP) { EDGE_LOOP(LDSIDX) } else { EDGE_LOOP(GLOBIDX) }
#undef LDSIDX
#undef GLOBIDX
#undef EDGE_LOOP

    // convert + swizzled store of the wave's 16 rows
    unsigned short* lb = lds_a + wid * 16 * CH;
#pragma unroll
    for (int r = 0; r < 16; ++r) {
        ushort4 w;
        w.x = f2bf(acc[r].x); w.y = f2bf(acc[r].y);
        w.z = f2bf(acc[r].z); w.w = f2bf(acc[r].w);
        const int gs = (lane >> 1) ^ (r & 7);   // 16B-group swizzle
        *reinterpret_cast<ushort4*>(lb + r * CH + gs * 8 + (lane & 1) * 4) = w;
    }
    __syncthreads();

    // ---- phase 2: MFMA ----
    f32x4 facc[4][4];
#pragma unroll
    for (int m = 0; m < 4; ++m)
#pragma unroll
        for (int nt = 0; nt < 4; ++nt) facc[m][nt] = (f32x4){0.f, 0.f, 0.f, 0.f};

    const unsigned short* wb = Wt + (size_t)(wid * 64 + r16) * CH + q * 8;

#pragma unroll
    for (int kk = 0; kk < 8; ++kk) {
        bf16x8 b[4];
#pragma unroll
        for (int nt = 0; nt < 4; ++nt)
            b[nt] = *reinterpret_cast<const bf16x8*>(wb + (size_t)nt * 16 * CH + kk * 32);
        bf16x8 a[4];
#pragma unroll
        for (int m = 0; m < 4; ++m) {
            const int lr = m * 16 + r16;
            const int idx = lr * CH + ((((kk * 4) + q) ^ (lr & 7)) << 3);
            a[m] = *reinterpret_cast<const bf16x8*>(&lds_a[idx]);
        }
#pragma unroll
        for (int m = 0; m < 4; ++m)
#pragma unroll
            for (int nt = 0; nt < 4; ++nt)
                facc[m][nt] = __builtin_amdgcn_mfma_f32_16x16x32_bf16(a[m], b[nt], facc[m][nt], 0, 0, 0);
    }

    // epilogue: exact f32 row-scale by norm, then store
#pragma unroll
    for (int m = 0; m < 4; ++m) {
        const int crow = rb + m * 16 + q * 4;
#pragma unroll
        for (int nt = 0; nt < 4; ++nt) {
            float* po = out + (size_t)crow * CH + wid * 64 + nt * 16 + r16;
#pragma unroll
            for (int r = 0; r < 4; ++r) {
                const float nj = __shfl(nv, m * 16 + q * 4 + r);
                po[(size_t)r * CH] = facc[m][nt][r] * nj;
            }
        }
    }
}

extern "C" void kernel_launch(void* const* d_in, const int* in_sizes, int n_in,
                              void* d_out, int out_size, void* d_ws, size_t ws_size,
                              hipStream_t stream) {
    const float* x = (const float*)d_in[0];
    const int* se = (const int*)d_in[1];
    const int* te = (const int*)d_in[2];
    const float* norm = (const float*)d_in[3];
    const float* W = (const float*)d_in[4];
    float* out = (float*)d_out;

    char* ws = (char*)d_ws;
    unsigned short* Wt = (unsigned short*)ws;             // 128 KB
    int* deg   = (int*)(ws + 131072);                     // 800 KB
    int* off   = (int*)(ws + 931072);                     // 800 KB
    int* cur   = (int*)(ws + 1731072);                    // 800 KB
    int* elist = (int*)(ws + 2531072);                    // 2.4 MB
    int* bsum  = (int*)(ws + 4931072);                    // 1 KB

    hipMemsetAsync(deg, 0, NN * sizeof(int), stream);
    k_prep<<<512, 256, 0, stream>>>(W, Wt, te, deg);
    k_scanA<<<NBLK_SCAN, 256, 0, stream>>>(deg, off, bsum);
    k_scanB<<<1, 256, 0, stream>>>(bsum);
    k_scanC<<<NBLK_SCAN, 256, 0, stream>>>(off, bsum, cur);
    k_fill<<<(NE + 255) / 256, 256, 0, stream>>>(se, te, cur, elist);
    k_fgg<<<NN / 64, 256, 0, stream>>>(x, off, deg, elist, norm, Wt, out);
}

// Round 9
// 279.108 us; speedup vs baseline: 8.3196x; 1.0204x over previous
//
#include <hip/hip_runtime.h>
#include <hip/hip_bf16.h>

#define NN 200000
#define NE 600000
#define CH 256
#define NBLK_SCAN 196   // ceil(200000/1024)

typedef short bf16x8 __attribute__((ext_vector_type(8)));
typedef float f32x4 __attribute__((ext_vector_type(4)));
typedef unsigned short ushort8v __attribute__((ext_vector_type(8)));

__device__ __forceinline__ unsigned short f2bf(float f) {
    unsigned int u = __builtin_bit_cast(unsigned int, f);
    u = (u + 0x7FFFu + ((u >> 16) & 1u)) >> 16;
    return (unsigned short)u;
}
__device__ __forceinline__ float bf2f(unsigned short u) {
    unsigned int v = ((unsigned int)u) << 16;
    return __builtin_bit_cast(float, v);
}

// prep: W transpose->bf16 + degree count
__global__ __launch_bounds__(256) void k_prep(const float* __restrict__ W,
                                              unsigned short* __restrict__ Wt,
                                              const int* __restrict__ te,
                                              int* __restrict__ deg) {
    const int t = blockIdx.x * 256 + threadIdx.x;
    const int S = gridDim.x * 256;
    for (int e = t; e < NE; e += S) atomicAdd(&deg[te[e]], 1);
    for (int i = t; i < CH * CH; i += S) {
        int j = i >> 8, k = i & 255;
        Wt[j * CH + k] = f2bf(W[k * CH + j]);
    }
}

__global__ __launch_bounds__(256) void k_scanA(const int* __restrict__ deg,
                                               int* __restrict__ off,
                                               int* __restrict__ bsum) {
    __shared__ int ts[256];
    int tid = threadIdx.x;
    int base = blockIdx.x * 1024 + tid * 4;
    int v[4];
#pragma unroll
    for (int j = 0; j < 4; ++j) {
        int idx = base + j;
        v[j] = (idx < NN) ? deg[idx] : 0;
    }
    int tsum = v[0] + v[1] + v[2] + v[3];
    ts[tid] = tsum;
    __syncthreads();
    int x = tsum;
    for (int ofs = 1; ofs < 256; ofs <<= 1) {
        int y = (tid >= ofs) ? ts[tid - ofs] : 0;
        __syncthreads();
        x += y;
        ts[tid] = x;
        __syncthreads();
    }
    int run = x - tsum;
#pragma unroll
    for (int j = 0; j < 4; ++j) {
        int idx = base + j;
        if (idx < NN) off[idx] = run;
        run += v[j];
    }
    if (tid == 255) bsum[blockIdx.x] = x;
}

__global__ __launch_bounds__(256) void k_scanB(int* __restrict__ bsum) {
    __shared__ int ts[256];
    int tid = threadIdx.x;
    int v = (tid < NBLK_SCAN) ? bsum[tid] : 0;
    ts[tid] = v;
    __syncthreads();
    int x = v;
    for (int ofs = 1; ofs < 256; ofs <<= 1) {
        int y = (tid >= ofs) ? ts[tid - ofs] : 0;
        __syncthreads();
        x += y;
        ts[tid] = x;
        __syncthreads();
    }
    if (tid < NBLK_SCAN) bsum[tid] = x - v;
}

__global__ __launch_bounds__(256) void k_scanC(int* __restrict__ off,
                                               const int* __restrict__ bsum,
                                               int* __restrict__ cur) {
    int tid = threadIdx.x;
    int base = blockIdx.x * 1024 + tid * 4;
    int bo = bsum[blockIdx.x];
#pragma unroll
    for (int j = 0; j < 4; ++j) {
        int idx = base + j;
        if (idx < NN) {
            int o = off[idx] + bo;
            off[idx] = o;
            cur[idx] = o;
        }
    }
}

__global__ void k_fill(const int* __restrict__ se, const int* __restrict__ te,
                       int* __restrict__ cur, int* __restrict__ elist) {
    int e = blockIdx.x * 256 + threadIdx.x;
    if (e < NE) {
        int t = te[e];
        int pos = atomicAdd(&cur[t], 1);
        elist[pos] = se[e];
    }
}

// ---------------- Path A ----------------
// K1: Z = x @ W, Z stored bf16 row-major. Stage 64x256 f32 x-tile -> bf16
// swizzled LDS (converted once at stage time), then the proven MFMA loop.
__global__ __launch_bounds__(256, 2) void k_zw(const float* __restrict__ x,
                                               const unsigned short* __restrict__ Wt,
                                               unsigned short* __restrict__ zbf) {
    __shared__ unsigned short lds_a[64 * CH];  // 32 KB
    const int tid = threadIdx.x;
    const int wid = tid >> 6;
    const int lane = tid & 63;
    const int rb = blockIdx.x * 64;
    const int r16 = lane & 15;
    const int q = lane >> 4;

    // stage + convert: thread t handles floats [t*8, t*8+8) of each 2048-chunk
    const float* gx = x + (size_t)rb * CH;
#pragma unroll
    for (int i = 0; i < 8; ++i) {
        const int idx = i * 2048 + tid * 8;      // float index in 64x256 tile
        const int row = idx >> 8;
        const int col = idx & 255;               // multiple of 8
        float4 f0 = *reinterpret_cast<const float4*>(gx + idx);
        float4 f1 = *reinterpret_cast<const float4*>(gx + idx + 4);
        ushort8v w;
        w[0] = f2bf(f0.x); w[1] = f2bf(f0.y); w[2] = f2bf(f0.z); w[3] = f2bf(f0.w);
        w[4] = f2bf(f1.x); w[5] = f2bf(f1.y); w[6] = f2bf(f1.z); w[7] = f2bf(f1.w);
        const int gs = (col >> 3) ^ (row & 7);   // 16B-group swizzle
        *reinterpret_cast<ushort8v*>(&lds_a[row * CH + gs * 8]) = w;
    }
    __syncthreads();

    f32x4 acc[4][4];
#pragma unroll
    for (int m = 0; m < 4; ++m)
#pragma unroll
        for (int nt = 0; nt < 4; ++nt) acc[m][nt] = (f32x4){0.f, 0.f, 0.f, 0.f};

    const unsigned short* wb = Wt + (size_t)(wid * 64 + r16) * CH + q * 8;

#pragma unroll
    for (int kk = 0; kk < 8; ++kk) {
        bf16x8 b[4];
#pragma unroll
        for (int nt = 0; nt < 4; ++nt)
            b[nt] = *reinterpret_cast<const bf16x8*>(wb + (size_t)nt * 16 * CH + kk * 32);
        bf16x8 a[4];
#pragma unroll
        for (int m = 0; m < 4; ++m) {
            const int lr = m * 16 + r16;
            const int idx = lr * CH + ((((kk * 4) + q) ^ (lr & 7)) << 3);
            a[m] = *reinterpret_cast<const bf16x8*>(&lds_a[idx]);
        }
#pragma unroll
        for (int m = 0; m < 4; ++m)
#pragma unroll
            for (int nt = 0; nt < 4; ++nt)
                acc[m][nt] = __builtin_amdgcn_mfma_f32_16x16x32_bf16(a[m], b[nt], acc[m][nt], 0, 0, 0);
    }

    // epilogue: Z as bf16; lanes 0-15 write 16 contiguous ushorts (32 B)
#pragma unroll
    for (int m = 0; m < 4; ++m) {
        const int crow = rb + m * 16 + q * 4;
#pragma unroll
        for (int nt = 0; nt < 4; ++nt) {
            unsigned short* po = zbf + (size_t)crow * CH + wid * 64 + nt * 16 + r16;
#pragma unroll
            for (int r = 0; r < 4; ++r) po[(size_t)r * CH] = f2bf(acc[m][nt][r]);
        }
    }
}

// K2: out[row] = norm[row] * (Z[row] + sum_e Z[elist[e]]), f32 out.
// One wave per row; unroll-8 edge index prefetch; bf16 Z reads (8B/lane).
__global__ __launch_bounds__(256) void k_gout(const unsigned short* __restrict__ zbf,
                                              const int* __restrict__ off,
                                              const int* __restrict__ deg,
                                              const int* __restrict__ elist,
                                              const float* __restrict__ norm,
                                              float* __restrict__ out) {
    int wid = threadIdx.x >> 6;
    int lane = threadIdx.x & 63;
    int row = blockIdx.x * 4 + wid;
    if (row >= NN) return;
    int start = off[row];
    int d = deg[row];
    const int uo = lane * 4;
    ushort4 bv = *reinterpret_cast<const ushort4*>(zbf + (size_t)row * CH + uo);
    float ax = bf2f(bv.x), ay = bf2f(bv.y), az = bf2f(bv.z), aw = bf2f(bv.w);
    int e = 0;
    while (e < d) {
        int i0 = (e + 0 < d) ? elist[start + e + 0] : -1;
        int i1 = (e + 1 < d) ? elist[start + e + 1] : -1;
        int i2 = (e + 2 < d) ? elist[start + e + 2] : -1;
        int i3 = (e + 3 < d) ? elist[start + e + 3] : -1;
        int i4 = (e + 4 < d) ? elist[start + e + 4] : -1;
        int i5 = (e + 5 < d) ? elist[start + e + 5] : -1;
        int i6 = (e + 6 < d) ? elist[start + e + 6] : -1;
        int i7 = (e + 7 < d) ? elist[start + e + 7] : -1;
#define GACC(ii) if (ii >= 0) { \
            ushort4 v = *reinterpret_cast<const ushort4*>(zbf + (size_t)ii * CH + uo); \
            ax += bf2f(v.x); ay += bf2f(v.y); az += bf2f(v.z); aw += bf2f(v.w); }
        GACC(i0) GACC(i1) GACC(i2) GACC(i3) GACC(i4) GACC(i5) GACC(i6) GACC(i7)
#undef GACC
        e += 8;
    }
    const float nv = norm[row];
    float4 o;
    o.x = ax * nv; o.y = ay * nv; o.z = az * nv; o.w = aw * nv;
    *reinterpret_cast<float4*>(out + (size_t)row * CH + uo) = o;
}

// ---------------- Path B (fallback: R8 fused f32 kernel) ----------------
__global__ __launch_bounds__(256, 4) void k_fgg(const float* __restrict__ x,
                                                const int* __restrict__ off,
                                                const int* __restrict__ deg,
                                                const int* __restrict__ elist,
                                                const float* __restrict__ norm,
                                                const unsigned short* __restrict__ Wt,
                                                float* __restrict__ out) {
    __shared__ unsigned short lds_a[64 * CH];
    const int tid = threadIdx.x;
    const int wid = tid >> 6;
    const int lane = tid & 63;
    const int rb = blockIdx.x * 64;
    const int rowbase = rb + wid * 16;
    const int r16 = lane & 15;
    const int q = lane >> 4;
    const int fo4 = lane * 4;

    const int offv = off[rowbase + r16];
    const int degv = deg[rowbase + r16];
    const float nv = norm[rb + lane];

    float4 acc[16];
#pragma unroll
    for (int r = 0; r < 16; ++r)
        acc[r] = *reinterpret_cast<const float4*>(x + (size_t)(rowbase + r) * CH + fo4);

#pragma unroll
    for (int r = 0; r < 16; ++r) {
        const int start = __shfl(offv, r);
        const int d = __shfl(degv, r);
        int e = 0;
        while (e < d) {
            int i0 = (e + 0 < d) ? elist[start + e + 0] : -1;
            int i1 = (e + 1 < d) ? elist[start + e + 1] : -1;
            int i2 = (e + 2 < d) ? elist[start + e + 2] : -1;
            int i3 = (e + 3 < d) ? elist[start + e + 3] : -1;
#define GACC(ii) if (ii >= 0) { \
            float4 v = *reinterpret_cast<const float4*>(x + (size_t)ii * CH + fo4); \
            acc[r].x += v.x; acc[r].y += v.y; acc[r].z += v.z; acc[r].w += v.w; }
            GACC(i0) GACC(i1) GACC(i2) GACC(i3)
#undef GACC
            e += 4;
        }
    }

    unsigned short* lb = lds_a + wid * 16 * CH;
#pragma unroll
    for (int r = 0; r < 16; ++r) {
        ushort4 w;
        w.x = f2bf(acc[r].x); w.y = f2bf(acc[r].y);
        w.z = f2bf(acc[r].z); w.w = f2bf(acc[r].w);
        const int gs = (lane >> 1) ^ (r & 7);
        *reinterpret_cast<ushort4*>(lb + r * CH + gs * 8 + (lane & 1) * 4) = w;
    }
    __syncthreads();

    f32x4 facc[4][4];
#pragma unroll
    for (int m = 0; m < 4; ++m)
#pragma unroll
        for (int nt = 0; nt < 4; ++nt) facc[m][nt] = (f32x4){0.f, 0.f, 0.f, 0.f};

    const unsigned short* wb = Wt + (size_t)(wid * 64 + r16) * CH + q * 8;

#pragma unroll
    for (int kk = 0; kk < 8; ++kk) {
        bf16x8 b[4];
#pragma unroll
        for (int nt = 0; nt < 4; ++nt)
            b[nt] = *reinterpret_cast<const bf16x8*>(wb + (size_t)nt * 16 * CH + kk * 32);
        bf16x8 a[4];
#pragma unroll
        for (int m = 0; m < 4; ++m) {
            const int lr = m * 16 + r16;
            const int idx = lr * CH + ((((kk * 4) + q) ^ (lr & 7)) << 3);
            a[m] = *reinterpret_cast<const bf16x8*>(&lds_a[idx]);
        }
#pragma unroll
        for (int m = 0; m < 4; ++m)
#pragma unroll
            for (int nt = 0; nt < 4; ++nt)
                facc[m][nt] = __builtin_amdgcn_mfma_f32_16x16x32_bf16(a[m], b[nt], facc[m][nt], 0, 0, 0);
    }

#pragma unroll
    for (int m = 0; m < 4; ++m) {
        const int crow = rb + m * 16 + q * 4;
#pragma unroll
        for (int nt = 0; nt < 4; ++nt) {
            float* po = out + (size_t)crow * CH + wid * 64 + nt * 16 + r16;
#pragma unroll
            for (int r = 0; r < 4; ++r) {
                const float nj = __shfl(nv, m * 16 + q * 4 + r);
                po[(size_t)r * CH] = facc[m][nt][r] * nj;
            }
        }
    }
}

extern "C" void kernel_launch(void* const* d_in, const int* in_sizes, int n_in,
                              void* d_out, int out_size, void* d_ws, size_t ws_size,
                              hipStream_t stream) {
    const float* x = (const float*)d_in[0];
    const int* se = (const int*)d_in[1];
    const int* te = (const int*)d_in[2];
    const float* norm = (const float*)d_in[3];
    const float* W = (const float*)d_in[4];
    float* out = (float*)d_out;

    char* ws = (char*)d_ws;
    unsigned short* Wt = (unsigned short*)ws;             // 128 KB
    int* deg   = (int*)(ws + 131072);                     // 800 KB
    int* off   = (int*)(ws + 931072);                     // 800 KB
    int* cur   = (int*)(ws + 1731072);                    // 800 KB
    int* elist = (int*)(ws + 2531072);                    // 2.4 MB
    int* bsum  = (int*)(ws + 4931072);                    // 1 KB
    const size_t ZBF_OFF = 4932096;
    const size_t NEED = ZBF_OFF + (size_t)NN * CH * 2;    // ~107.3 MB
    const bool big = (ws_size >= NEED);
    unsigned short* zbf = (unsigned short*)(ws + ZBF_OFF);

    hipMemsetAsync(deg, 0, NN * sizeof(int), stream);
    k_prep<<<512, 256, 0, stream>>>(W, Wt, te, deg);
    k_scanA<<<NBLK_SCAN, 256, 0, stream>>>(deg, off, bsum);
    k_scanB<<<1, 256, 0, stream>>>(bsum);
    k_scanC<<<NBLK_SCAN, 256, 0, stream>>>(off, bsum, cur);
    k_fill<<<(NE + 255) / 256, 256, 0, stream>>>(se, te, cur, elist);
    if (big) {
        k_zw<<<NN / 64, 256, 0, stream>>>(x, Wt, zbf);
        k_gout<<<NN / 4, 256, 0, stream>>>(zbf, off, deg, elist, norm, out);
    } else {
        k_fgg<<<NN / 64, 256, 0, stream>>>(x, off, deg, elist, norm, Wt, out);
    }
}